// Round 1
// baseline (8481.470 us; speedup 1.0000x reference)
//
#include <hip/hip_runtime.h>

#define NNODES 50000
#define NEDGES 800000
#define HD 256

typedef __attribute__((ext_vector_type(8))) short bf16x8;
typedef __attribute__((ext_vector_type(4))) float f32x4;

__device__ __forceinline__ unsigned int f2bf(float f) {
    union { float f; unsigned int u; } v; v.f = f;
    unsigned int u = v.u;
    u += 0x7fffu + ((u >> 16) & 1u);
    return u >> 16;
}

__global__ void fill_zero(float4* __restrict__ p) {
    int i = blockIdx.x * blockDim.x + threadIdx.x;
    p[i] = make_float4(0.f, 0.f, 0.f, 0.f);
}

// Pack 11 HxH fp32 matrices into bf16 MFMA B-fragment order:
// Wpk[mat][ct][kb][lane][j] = W[kb*32 + (lane>>4)*8 + j][ct*16 + (lane&15)]
__global__ void pack_w(const float* __restrict__ Wm, const float* __restrict__ pW1,
                       const float* __restrict__ pW2, unsigned short* __restrict__ Wpk) {
    int g = blockIdx.x * 256 + threadIdx.x;   // 11 * 65536 total
    int mat = g >> 16;
    int r = g & 65535;
    int j = r & 7, lane = (r >> 3) & 63, kb = (r >> 9) & 7, ct = r >> 12;
    int k = kb * 32 + ((lane >> 4) << 3) + j;
    int c = ct * 16 + (lane & 15);
    const float* s = (mat < 9) ? (Wm + (size_t)mat * 65536)
                               : ((mat == 9) ? pW1 : pW2);
    Wpk[g] = (unsigned short)f2bf(s[k * 256 + c]);
}

// One wave per edge; lane handles 4 columns. msg = relu(x[src] + ea@We + be),
// atomically accumulated into agg[dst].
__global__ __launch_bounds__(256) void edge_kernel(
    const float* __restrict__ x, const int* __restrict__ src,
    const int* __restrict__ dst, const float* __restrict__ ea,
    const float* __restrict__ We, const float* __restrict__ be,
    float* __restrict__ agg) {
    int e = blockIdx.x * 4 + (threadIdx.x >> 6);
    int lane = threadIdx.x & 63;
    int s = src[e];
    int d = dst[e];
    float a0 = ea[e * 3 + 0];
    float a1 = ea[e * 3 + 1];
    float a2 = ea[e * 3 + 2];
    int c = lane * 4;
    const float4 xs = *reinterpret_cast<const float4*>(x + (size_t)s * HD + c);
    const float4 w0 = *reinterpret_cast<const float4*>(We + c);
    const float4 w1 = *reinterpret_cast<const float4*>(We + HD + c);
    const float4 w2 = *reinterpret_cast<const float4*>(We + 2 * HD + c);
    const float4 bb = *reinterpret_cast<const float4*>(be + c);
    float m0 = fmaxf(xs.x + a0 * w0.x + a1 * w1.x + a2 * w2.x + bb.x, 0.f);
    float m1 = fmaxf(xs.y + a0 * w0.y + a1 * w1.y + a2 * w2.y + bb.y, 0.f);
    float m2 = fmaxf(xs.z + a0 * w0.z + a1 * w1.z + a2 * w2.z + bb.z, 0.f);
    float m3 = fmaxf(xs.w + a0 * w0.w + a1 * w1.w + a2 * w2.w + bb.w, 0.f);
    float* ap = agg + (size_t)d * HD + c;
    unsafeAtomicAdd(ap + 0, m0);
    unsafeAtomicAdd(ap + 1, m1);
    unsafeAtomicAdd(ap + 2, m2);
    unsafeAtomicAdd(ap + 3, m3);
}

// out[r][c] = (relu?)( (A (+A2))[r] @ W + bias )[c] (+ res[r][c])
// BM=64 rows/block, BN=256 cols, 4 waves (one 64-col slice each),
// per-wave 4x4 tiles of v_mfma_f32_16x16x32_bf16.
template <bool ADD2, bool RELU, bool RES>
__global__ __launch_bounds__(256) void gemm_mfma(
    const float* __restrict__ A, const float* __restrict__ A2,
    const unsigned short* __restrict__ Wpk, const float* __restrict__ bias,
    const float* __restrict__ res, float* __restrict__ out) {
    __shared__ __align__(16) unsigned char lds[64 * 256 * 2];  // bf16 A tile, swizzled
    const int tid = threadIdx.x;
    const int rbase = blockIdx.x * 64;

    // Stage A (fp32 -> bf16) into LDS with XOR swizzle (byte ^= (row&7)<<4).
    for (int it = 0; it < 16; ++it) {
        int q = tid + it * 256;      // float4 slot in [64][64]
        int row = q >> 6;
        int k4 = q & 63;
        int grow = rbase + row;
        float4 v = make_float4(0.f, 0.f, 0.f, 0.f);
        if (grow < NNODES) {
            v = *reinterpret_cast<const float4*>(A + (size_t)grow * HD + k4 * 4);
            if (ADD2) {
                float4 w = *reinterpret_cast<const float4*>(A2 + (size_t)grow * HD + k4 * 4);
                v.x += w.x; v.y += w.y; v.z += w.z; v.w += w.w;
            }
        }
        unsigned int lo = f2bf(v.x) | (f2bf(v.y) << 16);
        unsigned int hi = f2bf(v.z) | (f2bf(v.w) << 16);
        int kbyte = k4 * 8;
        int off = row * 512 + (kbyte ^ ((row & 7) << 4));
        *reinterpret_cast<uint2*>(lds + off) = make_uint2(lo, hi);
    }
    __syncthreads();

    const int wave = tid >> 6;
    const int lane = tid & 63;
    const int lr = lane & 15;   // A row-in-tile / B col / C col
    const int lg = lane >> 4;   // k-group / C row-group

    f32x4 acc[4][4];
#pragma unroll
    for (int rt = 0; rt < 4; ++rt)
#pragma unroll
        for (int ct = 0; ct < 4; ++ct) acc[rt][ct] = (f32x4){0.f, 0.f, 0.f, 0.f};

#pragma unroll
    for (int kb = 0; kb < 8; ++kb) {
        bf16x8 a[4], b[4];
#pragma unroll
        for (int rt = 0; rt < 4; ++rt) {
            int row = rt * 16 + lr;
            int kbyte = kb * 64 + lg * 16;
            int off = row * 512 + (kbyte ^ ((row & 7) << 4));
            a[rt] = *reinterpret_cast<const bf16x8*>(lds + off);
        }
#pragma unroll
        for (int ct = 0; ct < 4; ++ct) {
            const unsigned short* p =
                Wpk + ((size_t)(((wave * 4 + ct) * 8 + kb) * 64 + lane)) * 8;
            b[ct] = *reinterpret_cast<const bf16x8*>(p);
        }
#pragma unroll
        for (int rt = 0; rt < 4; ++rt)
#pragma unroll
            for (int ct = 0; ct < 4; ++ct)
                acc[rt][ct] = __builtin_amdgcn_mfma_f32_16x16x32_bf16(
                    a[rt], b[ct], acc[rt][ct], 0, 0, 0);
    }

    // Epilogue: C layout col = lane&15, row = (lane>>4)*4 + i
#pragma unroll
    for (int rt = 0; rt < 4; ++rt) {
        int row0 = rbase + rt * 16 + lg * 4;
#pragma unroll
        for (int ct = 0; ct < 4; ++ct) {
            int c = wave * 64 + ct * 16 + lr;
            float bv = bias[c];
#pragma unroll
            for (int i = 0; i < 4; ++i) {
                int row = row0 + i;
                if (row < NNODES) {
                    float v = acc[rt][ct][i] + bv;
                    if (RELU) v = fmaxf(v, 0.f);
                    if (RES) v += res[(size_t)row * HD + c];
                    out[(size_t)row * HD + c] = v;
                }
            }
        }
    }
}

extern "C" void kernel_launch(void* const* d_in, const int* in_sizes, int n_in,
                              void* d_out, int out_size, void* d_ws, size_t ws_size,
                              hipStream_t stream) {
    const float* x   = (const float*)d_in[0];
    const int*   ei  = (const int*)d_in[1];
    const float* ea  = (const float*)d_in[2];
    const float* We  = (const float*)d_in[3];
    const float* be  = (const float*)d_in[4];
    const float* Wm  = (const float*)d_in[5];
    const float* bm  = (const float*)d_in[6];
    const float* pW1 = (const float*)d_in[7];
    const float* pb1 = (const float*)d_in[8];
    const float* pW2 = (const float*)d_in[9];
    const float* pb2 = (const float*)d_in[10];
    float* out = (float*)d_out;

    const size_t NH = (size_t)NNODES * HD;  // 12.8M floats
    float* cur = (float*)d_ws;
    float* agg = cur + NH;
    float* t0  = agg + NH;
    unsigned short* Wpk = (unsigned short*)(t0 + NH);

    hipMemcpyAsync(cur, x, NH * sizeof(float), hipMemcpyDeviceToDevice, stream);
    pack_w<<<dim3(11 * 65536 / 256), dim3(256), 0, stream>>>(Wm, pW1, pW2, Wpk);

    const int* srcI = ei;            // edge_index[0]
    const int* dstI = ei + NEDGES;   // edge_index[1]
    const int gemm_grid = (NNODES + 63) / 64;

    for (int l = 0; l < 3; ++l) {
        fill_zero<<<dim3(NH / 4 / 256), dim3(256), 0, stream>>>((float4*)agg);
        edge_kernel<<<dim3(NEDGES / 4), dim3(256), 0, stream>>>(
            cur, srcI, dstI, ea, We + (size_t)l * 3 * HD, be + (size_t)l * HD, agg);
        gemm_mfma<true, true, false><<<dim3(gemm_grid), dim3(256), 0, stream>>>(
            cur, agg, Wpk + (size_t)(l * 3 + 0) * 65536, bm + (size_t)(l * 3 + 0) * HD,
            nullptr, t0);
        gemm_mfma<false, true, false><<<dim3(gemm_grid), dim3(256), 0, stream>>>(
            t0, nullptr, Wpk + (size_t)(l * 3 + 1) * 65536, bm + (size_t)(l * 3 + 1) * HD,
            nullptr, t0);
        gemm_mfma<false, true, true><<<dim3(gemm_grid), dim3(256), 0, stream>>>(
            t0, nullptr, Wpk + (size_t)(l * 3 + 2) * 65536, bm + (size_t)(l * 3 + 2) * HD,
            cur, cur);
    }
    gemm_mfma<false, true, false><<<dim3(gemm_grid), dim3(256), 0, stream>>>(
        cur, nullptr, Wpk + (size_t)9 * 65536, pb1, nullptr, t0);
    gemm_mfma<false, false, false><<<dim3(gemm_grid), dim3(256), 0, stream>>>(
        t0, nullptr, Wpk + (size_t)10 * 65536, pb2, nullptr, out);
}

// Round 2
// 1037.861 us; speedup vs baseline: 8.1721x; 8.1721x over previous
//
#include <hip/hip_runtime.h>

#define NNODES 50000
#define NEDGES 800000
#define HD 256

typedef __attribute__((ext_vector_type(8))) short bf16x8;
typedef __attribute__((ext_vector_type(4))) float f32x4;

__device__ __forceinline__ unsigned int f2bf(float f) {
    union { float f; unsigned int u; } v; v.f = f;
    unsigned int u = v.u;
    u += 0x7fffu + ((u >> 16) & 1u);
    return u >> 16;
}

__global__ void zero_int(int* __restrict__ p, int n) {
    int i = blockIdx.x * blockDim.x + threadIdx.x;
    if (i < n) p[i] = 0;
}

__global__ __launch_bounds__(256) void hist_kernel(const int* __restrict__ dst,
                                                   int* __restrict__ deg) {
    int e = blockIdx.x * 256 + threadIdx.x;
    if (e < NEDGES) atomicAdd(&deg[dst[e]], 1);
}

// Single-block exclusive scan of deg[0..NNODES) -> rowptr/cursor; rowptr[NNODES]=total.
__global__ __launch_bounds__(1024) void scan_kernel(const int* __restrict__ deg,
                                                    int* __restrict__ rowptr,
                                                    int* __restrict__ cursor) {
    __shared__ int sums[1024];
    const int t = threadIdx.x;
    const int CH = 49;  // 1024*49 = 50176 >= NNODES
    int base = t * CH;
    int s = 0;
    for (int i = 0; i < CH; ++i) {
        int idx = base + i;
        if (idx < NNODES) s += deg[idx];
    }
    sums[t] = s;
    __syncthreads();
    for (int off = 1; off < 1024; off <<= 1) {
        int v = (t >= off) ? sums[t - off] : 0;
        __syncthreads();
        sums[t] += v;
        __syncthreads();
    }
    int run = (t == 0) ? 0 : sums[t - 1];
    for (int i = 0; i < CH; ++i) {
        int idx = base + i;
        if (idx < NNODES) {
            rowptr[idx] = run;
            cursor[idx] = run;
            run += deg[idx];
        }
    }
    if (t == 1023) rowptr[NNODES] = sums[1023];
}

// epack[pos] = {src, ea0, ea1, ea2} in dst-bucketed (CSR) order.
__global__ __launch_bounds__(256) void fill_csr(const int* __restrict__ src,
                                                const int* __restrict__ dst,
                                                const float* __restrict__ ea,
                                                int* __restrict__ cursor,
                                                int4* __restrict__ epack) {
    int e = blockIdx.x * 256 + threadIdx.x;
    if (e >= NEDGES) return;
    int pos = atomicAdd(&cursor[dst[e]], 1);
    int4 v;
    v.x = src[e];
    v.y = __float_as_int(ea[e * 3 + 0]);
    v.z = __float_as_int(ea[e * 3 + 1]);
    v.w = __float_as_int(ea[e * 3 + 2]);
    epack[pos] = v;
}

// out[n] = x[n] + sum_{e in CSR[n]} relu(x[src_e] + ea_e @ We + be)
// One wave per node; lane owns 4 contiguous columns (float4).
__global__ __launch_bounds__(256) void agg_kernel(
    const float* __restrict__ x, const int* __restrict__ rowptr,
    const int4* __restrict__ epack, const float* __restrict__ We,
    const float* __restrict__ be, float* __restrict__ out) {
    const int wave = threadIdx.x >> 6;
    const int lane = threadIdx.x & 63;
    const int n = blockIdx.x * 4 + wave;
    const int c = lane * 4;
    const float4 w0 = *reinterpret_cast<const float4*>(We + c);
    const float4 w1 = *reinterpret_cast<const float4*>(We + HD + c);
    const float4 w2 = *reinterpret_cast<const float4*>(We + 2 * HD + c);
    const float4 bb = *reinterpret_cast<const float4*>(be + c);
    float4 acc = *reinterpret_cast<const float4*>(x + (size_t)n * HD + c);
    int beg = rowptr[n], end = rowptr[n + 1];
    int4 ep = (beg < end) ? epack[beg] : make_int4(0, 0, 0, 0);
    for (int i = beg; i < end; ++i) {
        int4 e = ep;
        if (i + 1 < end) ep = epack[i + 1];  // prefetch next edge record
        float a0 = __int_as_float(e.y);
        float a1 = __int_as_float(e.z);
        float a2 = __int_as_float(e.w);
        const float4 xs = *reinterpret_cast<const float4*>(x + (size_t)e.x * HD + c);
        acc.x += fmaxf(fmaf(a0, w0.x, fmaf(a1, w1.x, fmaf(a2, w2.x, xs.x + bb.x))), 0.f);
        acc.y += fmaxf(fmaf(a0, w0.y, fmaf(a1, w1.y, fmaf(a2, w2.y, xs.y + bb.y))), 0.f);
        acc.z += fmaxf(fmaf(a0, w0.z, fmaf(a1, w1.z, fmaf(a2, w2.z, xs.z + bb.z))), 0.f);
        acc.w += fmaxf(fmaf(a0, w0.w, fmaf(a1, w1.w, fmaf(a2, w2.w, xs.w + bb.w))), 0.f);
    }
    *reinterpret_cast<float4*>(out + (size_t)n * HD + c) = acc;
}

// Pack 11 HxH fp32 matrices into bf16 MFMA B-fragment order:
// Wpk[mat][ct][kb][lane][j] = W[kb*32 + (lane>>4)*8 + j][ct*16 + (lane&15)]
__global__ void pack_w(const float* __restrict__ Wm, const float* __restrict__ pW1,
                       const float* __restrict__ pW2, unsigned short* __restrict__ Wpk) {
    int g = blockIdx.x * 256 + threadIdx.x;  // 11 * 65536 total
    int mat = g >> 16;
    int r = g & 65535;
    int j = r & 7, lane = (r >> 3) & 63, kb = (r >> 9) & 7, ct = r >> 12;
    int k = kb * 32 + ((lane >> 4) << 3) + j;
    int c = ct * 16 + (lane & 15);
    const float* s = (mat < 9) ? (Wm + (size_t)mat * 65536)
                               : ((mat == 9) ? pW1 : pW2);
    Wpk[g] = (unsigned short)f2bf(s[k * 256 + c]);
}

// out[r][c] = (relu?)( A[r] @ W + bias )[c] (+ res[r][c])
// BM=64 rows/block, BN=256 cols, 4 waves, 4x4 tiles of v_mfma_f32_16x16x32_bf16.
template <bool RELU, bool RES>
__global__ __launch_bounds__(256) void gemm_mfma(
    const float* __restrict__ A, const unsigned short* __restrict__ Wpk,
    const float* __restrict__ bias, const float* __restrict__ res,
    float* __restrict__ out) {
    __shared__ __align__(16) unsigned char lds[64 * 256 * 2];  // bf16 A tile, swizzled
    const int tid = threadIdx.x;
    const int rbase = blockIdx.x * 64;

    for (int it = 0; it < 16; ++it) {
        int q = tid + it * 256;  // float4 slot in [64][64]
        int row = q >> 6;
        int k4 = q & 63;
        int grow = rbase + row;
        float4 v = make_float4(0.f, 0.f, 0.f, 0.f);
        if (grow < NNODES)
            v = *reinterpret_cast<const float4*>(A + (size_t)grow * HD + k4 * 4);
        unsigned int lo = f2bf(v.x) | (f2bf(v.y) << 16);
        unsigned int hi = f2bf(v.z) | (f2bf(v.w) << 16);
        int kbyte = k4 * 8;
        int off = row * 512 + (kbyte ^ ((row & 7) << 4));
        *reinterpret_cast<uint2*>(lds + off) = make_uint2(lo, hi);
    }
    __syncthreads();

    const int wave = tid >> 6;
    const int lane = tid & 63;
    const int lr = lane & 15;
    const int lg = lane >> 4;

    f32x4 acc[4][4];
#pragma unroll
    for (int rt = 0; rt < 4; ++rt)
#pragma unroll
        for (int ct = 0; ct < 4; ++ct) acc[rt][ct] = (f32x4){0.f, 0.f, 0.f, 0.f};

#pragma unroll
    for (int kb = 0; kb < 8; ++kb) {
        bf16x8 a[4], b[4];
#pragma unroll
        for (int rt = 0; rt < 4; ++rt) {
            int row = rt * 16 + lr;
            int kbyte = kb * 64 + lg * 16;
            int off = row * 512 + (kbyte ^ ((row & 7) << 4));
            a[rt] = *reinterpret_cast<const bf16x8*>(lds + off);
        }
#pragma unroll
        for (int ct = 0; ct < 4; ++ct) {
            const unsigned short* p =
                Wpk + ((size_t)(((wave * 4 + ct) * 8 + kb) * 64 + lane)) * 8;
            b[ct] = *reinterpret_cast<const bf16x8*>(p);
        }
#pragma unroll
        for (int rt = 0; rt < 4; ++rt)
#pragma unroll
            for (int ct = 0; ct < 4; ++ct)
                acc[rt][ct] = __builtin_amdgcn_mfma_f32_16x16x32_bf16(
                    a[rt], b[ct], acc[rt][ct], 0, 0, 0);
    }

#pragma unroll
    for (int rt = 0; rt < 4; ++rt) {
        int row0 = rbase + rt * 16 + lg * 4;
#pragma unroll
        for (int ct = 0; ct < 4; ++ct) {
            int c = wave * 64 + ct * 16 + lr;
            float bv = bias[c];
#pragma unroll
            for (int i = 0; i < 4; ++i) {
                int row = row0 + i;
                if (row < NNODES) {
                    float v = acc[rt][ct][i] + bv;
                    if (RELU) v = fmaxf(v, 0.f);
                    if (RES) v += res[(size_t)row * HD + c];
                    out[(size_t)row * HD + c] = v;
                }
            }
        }
    }
}

extern "C" void kernel_launch(void* const* d_in, const int* in_sizes, int n_in,
                              void* d_out, int out_size, void* d_ws, size_t ws_size,
                              hipStream_t stream) {
    const float* x   = (const float*)d_in[0];
    const int*   ei  = (const int*)d_in[1];
    const float* ea  = (const float*)d_in[2];
    const float* We  = (const float*)d_in[3];
    const float* be  = (const float*)d_in[4];
    const float* Wm  = (const float*)d_in[5];
    const float* bm  = (const float*)d_in[6];
    const float* pW1 = (const float*)d_in[7];
    const float* pb1 = (const float*)d_in[8];
    const float* pW2 = (const float*)d_in[9];
    const float* pb2 = (const float*)d_in[10];
    float* out = (float*)d_out;

    const size_t NH = (size_t)NNODES * HD;  // 12.8M floats
    float* cur = (float*)d_ws;
    float* agg = cur + NH;
    float* t0  = agg + NH;
    unsigned short* Wpk = (unsigned short*)(t0 + NH);       // 11*65536 shorts
    int* rowptr = (int*)(Wpk + 11 * 65536);                 // NNODES+1
    int* cursor = rowptr + 50004;
    int* deg    = cursor + 50004;
    int4* epack = (int4*)d_out;  // scratch until head GEMMs; 800k*16B <= out buffer

    const int* srcI = ei;           // edge_index[0]
    const int* dstI = ei + NEDGES;  // edge_index[1]

    // --- Build CSR (once) + pack weights ---
    zero_int<<<dim3((NNODES + 255) / 256), dim3(256), 0, stream>>>(deg, NNODES);
    pack_w<<<dim3(11 * 65536 / 256), dim3(256), 0, stream>>>(Wm, pW1, pW2, Wpk);
    hist_kernel<<<dim3((NEDGES + 255) / 256), dim3(256), 0, stream>>>(dstI, deg);
    scan_kernel<<<dim3(1), dim3(1024), 0, stream>>>(deg, rowptr, cursor);
    fill_csr<<<dim3((NEDGES + 255) / 256), dim3(256), 0, stream>>>(srcI, dstI, ea,
                                                                   cursor, epack);

    const int gemm_grid = (NNODES + 63) / 64;
    for (int l = 0; l < 3; ++l) {
        const float* xin = (l == 0) ? x : cur;
        agg_kernel<<<dim3(NNODES / 4), dim3(256), 0, stream>>>(
            xin, rowptr, epack, We + (size_t)l * 3 * HD, be + (size_t)l * HD, agg);
        gemm_mfma<true, false><<<dim3(gemm_grid), dim3(256), 0, stream>>>(
            agg, Wpk + (size_t)(l * 3 + 0) * 65536, bm + (size_t)(l * 3 + 0) * HD,
            nullptr, t0);
        gemm_mfma<true, false><<<dim3(gemm_grid), dim3(256), 0, stream>>>(
            t0, Wpk + (size_t)(l * 3 + 1) * 65536, bm + (size_t)(l * 3 + 1) * HD,
            nullptr, t0);
        gemm_mfma<true, true><<<dim3(gemm_grid), dim3(256), 0, stream>>>(
            t0, Wpk + (size_t)(l * 3 + 2) * 65536, bm + (size_t)(l * 3 + 2) * HD,
            xin, cur);
    }
    gemm_mfma<true, false><<<dim3(gemm_grid), dim3(256), 0, stream>>>(
        cur, Wpk + (size_t)9 * 65536, pb1, nullptr, t0);
    gemm_mfma<false, false><<<dim3(gemm_grid), dim3(256), 0, stream>>>(
        t0, Wpk + (size_t)10 * 65536, pb2, nullptr, out);
}

// Round 3
// 888.090 us; speedup vs baseline: 9.5502x; 1.1686x over previous
//
#include <hip/hip_runtime.h>

#define NNODES 50000
#define NEDGES 800000
#define HD 256

typedef __attribute__((ext_vector_type(8))) short bf16x8;
typedef __attribute__((ext_vector_type(4))) float f32x4;

__device__ __forceinline__ unsigned int f2bf(float f) {
    union { float f; unsigned int u; } v; v.f = f;
    unsigned int u = v.u;
    u += 0x7fffu + ((u >> 16) & 1u);
    return u >> 16;
}
__device__ __forceinline__ float b2f(unsigned short u) {
    union { unsigned int u; float f; } v; v.u = ((unsigned int)u) << 16;
    return v.f;
}

__global__ void zero_int(int* __restrict__ p, int n) {
    int i = blockIdx.x * blockDim.x + threadIdx.x;
    if (i < n) p[i] = 0;
}

// fp32 -> bf16 conversion, 4 elems/thread
__global__ __launch_bounds__(256) void x2bf(const float* __restrict__ x,
                                            unsigned short* __restrict__ xb) {
    int i = blockIdx.x * 256 + threadIdx.x;
    float4 v = reinterpret_cast<const float4*>(x)[i];
    ushort4 o;
    o.x = (unsigned short)f2bf(v.x);
    o.y = (unsigned short)f2bf(v.y);
    o.z = (unsigned short)f2bf(v.z);
    o.w = (unsigned short)f2bf(v.w);
    reinterpret_cast<ushort4*>(xb)[i] = o;
}

__global__ __launch_bounds__(256) void hist_kernel(const int* __restrict__ dst,
                                                   int* __restrict__ deg) {
    int e = blockIdx.x * 256 + threadIdx.x;
    if (e < NEDGES) atomicAdd(&deg[dst[e]], 1);
}

// Single-block exclusive scan of deg -> rowptr/cursor.
__global__ __launch_bounds__(1024) void scan_kernel(const int* __restrict__ deg,
                                                    int* __restrict__ rowptr,
                                                    int* __restrict__ cursor) {
    __shared__ int sums[1024];
    const int t = threadIdx.x;
    const int CH = 49;
    int base = t * CH;
    int s = 0;
    for (int i = 0; i < CH; ++i) {
        int idx = base + i;
        if (idx < NNODES) s += deg[idx];
    }
    sums[t] = s;
    __syncthreads();
    for (int off = 1; off < 1024; off <<= 1) {
        int v = (t >= off) ? sums[t - off] : 0;
        __syncthreads();
        sums[t] += v;
        __syncthreads();
    }
    int run = (t == 0) ? 0 : sums[t - 1];
    for (int i = 0; i < CH; ++i) {
        int idx = base + i;
        if (idx < NNODES) {
            rowptr[idx] = run;
            cursor[idx] = run;
            run += deg[idx];
        }
    }
    if (t == 1023) rowptr[NNODES] = sums[1023];
}

__global__ __launch_bounds__(256) void fill_csr(const int* __restrict__ src,
                                                const int* __restrict__ dst,
                                                const float* __restrict__ ea,
                                                int* __restrict__ cursor,
                                                int4* __restrict__ epack) {
    int e = blockIdx.x * 256 + threadIdx.x;
    if (e >= NEDGES) return;
    int pos = atomicAdd(&cursor[dst[e]], 1);
    int4 v;
    v.x = src[e];
    v.y = __float_as_int(ea[e * 3 + 0]);
    v.z = __float_as_int(ea[e * 3 + 1]);
    v.w = __float_as_int(ea[e * 3 + 2]);
    epack[pos] = v;
}

// out[n] = x[n] + sum_{e in CSR[n]} relu(x[src_e] + ea_e @ We + be); all bf16 I/O.
__global__ __launch_bounds__(256) void agg_kernel(
    const unsigned short* __restrict__ xb, const int* __restrict__ rowptr,
    const int4* __restrict__ epack, const float* __restrict__ We,
    const float* __restrict__ be, unsigned short* __restrict__ out) {
    const int wave = threadIdx.x >> 6;
    const int lane = threadIdx.x & 63;
    const int n = blockIdx.x * 4 + wave;
    const int c = lane * 4;
    const float4 w0 = *reinterpret_cast<const float4*>(We + c);
    const float4 w1 = *reinterpret_cast<const float4*>(We + HD + c);
    const float4 w2 = *reinterpret_cast<const float4*>(We + 2 * HD + c);
    const float4 bb = *reinterpret_cast<const float4*>(be + c);
    ushort4 xv = *reinterpret_cast<const ushort4*>(xb + (size_t)n * HD + c);
    float4 acc = make_float4(b2f(xv.x), b2f(xv.y), b2f(xv.z), b2f(xv.w));
    int beg = rowptr[n], end = rowptr[n + 1];
    int4 ep = (beg < end) ? epack[beg] : make_int4(0, 0, 0, 0);
    for (int i = beg; i < end; ++i) {
        int4 e = ep;
        if (i + 1 < end) ep = epack[i + 1];
        float a0 = __int_as_float(e.y);
        float a1 = __int_as_float(e.z);
        float a2 = __int_as_float(e.w);
        ushort4 xs4 = *reinterpret_cast<const ushort4*>(xb + (size_t)e.x * HD + c);
        float sx = b2f(xs4.x), sy = b2f(xs4.y), sz = b2f(xs4.z), sw = b2f(xs4.w);
        acc.x += fmaxf(fmaf(a0, w0.x, fmaf(a1, w1.x, fmaf(a2, w2.x, sx + bb.x))), 0.f);
        acc.y += fmaxf(fmaf(a0, w0.y, fmaf(a1, w1.y, fmaf(a2, w2.y, sy + bb.y))), 0.f);
        acc.z += fmaxf(fmaf(a0, w0.z, fmaf(a1, w1.z, fmaf(a2, w2.z, sz + bb.z))), 0.f);
        acc.w += fmaxf(fmaf(a0, w0.w, fmaf(a1, w1.w, fmaf(a2, w2.w, sw + bb.w))), 0.f);
    }
    ushort4 o;
    o.x = (unsigned short)f2bf(acc.x);
    o.y = (unsigned short)f2bf(acc.y);
    o.z = (unsigned short)f2bf(acc.z);
    o.w = (unsigned short)f2bf(acc.w);
    *reinterpret_cast<ushort4*>(out + (size_t)n * HD + c) = o;
}

// Pack 11 HxH fp32 matrices into bf16 MFMA B-fragment order.
__global__ void pack_w(const float* __restrict__ Wm, const float* __restrict__ pW1,
                       const float* __restrict__ pW2, unsigned short* __restrict__ Wpk) {
    int g = blockIdx.x * 256 + threadIdx.x;  // 11 * 65536
    int mat = g >> 16;
    int r = g & 65535;
    int j = r & 7, lane = (r >> 3) & 63, kb = (r >> 9) & 7, ct = r >> 12;
    int k = kb * 32 + ((lane >> 4) << 3) + j;
    int c = ct * 16 + (lane & 15);
    const float* s = (mat < 9) ? (Wm + (size_t)mat * 65536)
                               : ((mat == 9) ? pW1 : pW2);
    Wpk[g] = (unsigned short)f2bf(s[k * 256 + c]);
}

// out[r][c] = (relu?)( A[r] @ W + bias )[c] (+ res[r][c]); A,res bf16; out bf16 or f32.
template <bool RELU, bool RES, bool OUTF32>
__global__ __launch_bounds__(256) void gemm_mfma(
    const unsigned short* __restrict__ A, const unsigned short* __restrict__ Wpk,
    const float* __restrict__ bias, const unsigned short* __restrict__ res,
    void* __restrict__ outv) {
    __shared__ __align__(16) unsigned char lds[64 * 256 * 2];
    const int tid = threadIdx.x;
    const int rbase = blockIdx.x * 64;

    for (int it = 0; it < 16; ++it) {
        int q = tid + it * 256;  // 4-col chunk in [64][64]
        int row = q >> 6;
        int k4 = q & 63;
        int grow = rbase + row;
        uint2 v = make_uint2(0u, 0u);
        if (grow < NNODES)
            v = *reinterpret_cast<const uint2*>(A + (size_t)grow * HD + k4 * 4);
        int off = row * 512 + ((k4 * 8) ^ ((row & 7) << 4));
        *reinterpret_cast<uint2*>(lds + off) = v;
    }
    __syncthreads();

    const int wave = tid >> 6;
    const int lane = tid & 63;
    const int lr = lane & 15;
    const int lg = lane >> 4;

    f32x4 acc[4][4];
#pragma unroll
    for (int rt = 0; rt < 4; ++rt)
#pragma unroll
        for (int ct = 0; ct < 4; ++ct) acc[rt][ct] = (f32x4){0.f, 0.f, 0.f, 0.f};

#pragma unroll
    for (int kb = 0; kb < 8; ++kb) {
        bf16x8 a[4], b[4];
#pragma unroll
        for (int rt = 0; rt < 4; ++rt) {
            int row = rt * 16 + lr;
            int kbyte = kb * 64 + lg * 16;
            int off = row * 512 + (kbyte ^ ((row & 7) << 4));
            a[rt] = *reinterpret_cast<const bf16x8*>(lds + off);
        }
#pragma unroll
        for (int ct = 0; ct < 4; ++ct) {
            const unsigned short* p =
                Wpk + ((size_t)(((wave * 4 + ct) * 8 + kb) * 64 + lane)) * 8;
            b[ct] = *reinterpret_cast<const bf16x8*>(p);
        }
#pragma unroll
        for (int rt = 0; rt < 4; ++rt)
#pragma unroll
            for (int ct = 0; ct < 4; ++ct)
                acc[rt][ct] = __builtin_amdgcn_mfma_f32_16x16x32_bf16(
                    a[rt], b[ct], acc[rt][ct], 0, 0, 0);
    }

#pragma unroll
    for (int rt = 0; rt < 4; ++rt) {
        int row0 = rbase + rt * 16 + lg * 4;
#pragma unroll
        for (int ct = 0; ct < 4; ++ct) {
            int c = wave * 64 + ct * 16 + lr;
            float bv = bias[c];
#pragma unroll
            for (int i = 0; i < 4; ++i) {
                int row = row0 + i;
                if (row < NNODES) {
                    float v = acc[rt][ct][i] + bv;
                    if (RELU) v = fmaxf(v, 0.f);
                    if (RES) v += b2f(res[(size_t)row * HD + c]);
                    if (OUTF32)
                        reinterpret_cast<float*>(outv)[(size_t)row * HD + c] = v;
                    else
                        reinterpret_cast<unsigned short*>(outv)[(size_t)row * HD + c] =
                            (unsigned short)f2bf(v);
                }
            }
        }
    }
}

extern "C" void kernel_launch(void* const* d_in, const int* in_sizes, int n_in,
                              void* d_out, int out_size, void* d_ws, size_t ws_size,
                              hipStream_t stream) {
    const float* x   = (const float*)d_in[0];
    const int*   ei  = (const int*)d_in[1];
    const float* ea  = (const float*)d_in[2];
    const float* We  = (const float*)d_in[3];
    const float* be  = (const float*)d_in[4];
    const float* Wm  = (const float*)d_in[5];
    const float* bm  = (const float*)d_in[6];
    const float* pW1 = (const float*)d_in[7];
    const float* pb1 = (const float*)d_in[8];
    const float* pW2 = (const float*)d_in[9];
    const float* pb2 = (const float*)d_in[10];
    float* out = (float*)d_out;

    const size_t NH = (size_t)NNODES * HD;  // 12.8M elems
    unsigned short* xb   = (unsigned short*)d_ws;
    unsigned short* curb = xb + NH;
    unsigned short* aggb = curb + NH;
    unsigned short* t0b  = aggb + NH;
    unsigned short* Wpk  = t0b + NH;            // 11*65536 shorts
    int* rowptr = (int*)(Wpk + 11 * 65536);     // NNODES+1
    int* cursor = rowptr + 50004;
    int* deg    = cursor + 50004;
    int4* epack = (int4*)d_out;  // scratch until the final GEMM writes d_out

    const int* srcI = ei;
    const int* dstI = ei + NEDGES;

    // --- One-time (per launch) prep ---
    x2bf<<<dim3(NH / 4 / 256), dim3(256), 0, stream>>>(x, xb);
    zero_int<<<dim3((NNODES + 255) / 256), dim3(256), 0, stream>>>(deg, NNODES);
    pack_w<<<dim3(11 * 65536 / 256), dim3(256), 0, stream>>>(Wm, pW1, pW2, Wpk);
    hist_kernel<<<dim3((NEDGES + 255) / 256), dim3(256), 0, stream>>>(dstI, deg);
    scan_kernel<<<dim3(1), dim3(1024), 0, stream>>>(deg, rowptr, cursor);
    fill_csr<<<dim3((NEDGES + 255) / 256), dim3(256), 0, stream>>>(srcI, dstI, ea,
                                                                   cursor, epack);

    const int gemm_grid = (NNODES + 63) / 64;
    for (int l = 0; l < 3; ++l) {
        const unsigned short* xin = (l == 0) ? xb : curb;
        agg_kernel<<<dim3(NNODES / 4), dim3(256), 0, stream>>>(
            xin, rowptr, epack, We + (size_t)l * 3 * HD, be + (size_t)l * HD, aggb);
        gemm_mfma<true, false, false><<<dim3(gemm_grid), dim3(256), 0, stream>>>(
            aggb, Wpk + (size_t)(l * 3 + 0) * 65536, bm + (size_t)(l * 3 + 0) * HD,
            nullptr, t0b);
        gemm_mfma<true, false, false><<<dim3(gemm_grid), dim3(256), 0, stream>>>(
            t0b, Wpk + (size_t)(l * 3 + 1) * 65536, bm + (size_t)(l * 3 + 1) * HD,
            nullptr, t0b);
        gemm_mfma<true, true, false><<<dim3(gemm_grid), dim3(256), 0, stream>>>(
            t0b, Wpk + (size_t)(l * 3 + 2) * 65536, bm + (size_t)(l * 3 + 2) * HD,
            xin, curb);
    }
    gemm_mfma<true, false, false><<<dim3(gemm_grid), dim3(256), 0, stream>>>(
        curb, Wpk + (size_t)9 * 65536, pb1, nullptr, t0b);
    gemm_mfma<false, false, true><<<dim3(gemm_grid), dim3(256), 0, stream>>>(
        t0b, Wpk + (size_t)10 * 65536, pb2, nullptr, out);
}

// Round 4
// 767.569 us; speedup vs baseline: 11.0498x; 1.1570x over previous
//
#include <hip/hip_runtime.h>

#define NNODES 50000
#define NEDGES 800000
#define HD 256
#define NSB 196  // scan blocks: 196*256 = 50176 >= NNODES+1

typedef __attribute__((ext_vector_type(8))) short bf16x8;
typedef __attribute__((ext_vector_type(4))) float f32x4;

__device__ __forceinline__ unsigned int f2bf(float f) {
    union { float f; unsigned int u; } v; v.f = f;
    unsigned int u = v.u;
    u += 0x7fffu + ((u >> 16) & 1u);
    return u >> 16;
}
__device__ __forceinline__ float b2f(unsigned short u) {
    union { unsigned int u; float f; } v; v.u = ((unsigned int)u) << 16;
    return v.f;
}

__global__ void zero_int(int* __restrict__ p, int n) {
    int i = blockIdx.x * blockDim.x + threadIdx.x;
    if (i < n) p[i] = 0;
}

__global__ __launch_bounds__(256) void x2bf(const float* __restrict__ x,
                                            unsigned short* __restrict__ xb) {
    int i = blockIdx.x * 256 + threadIdx.x;
    float4 v = reinterpret_cast<const float4*>(x)[i];
    ushort4 o;
    o.x = (unsigned short)f2bf(v.x);
    o.y = (unsigned short)f2bf(v.y);
    o.z = (unsigned short)f2bf(v.z);
    o.w = (unsigned short)f2bf(v.w);
    reinterpret_cast<ushort4*>(xb)[i] = o;
}

__global__ __launch_bounds__(256) void hist_kernel(const int* __restrict__ dst,
                                                   int* __restrict__ deg) {
    int e = blockIdx.x * 256 + threadIdx.x;
    if (e < NEDGES) atomicAdd(&deg[dst[e]], 1);
}

// --- 3-kernel exclusive scan of deg[0..NNODES) ---
__global__ __launch_bounds__(256) void scan_part(const int* __restrict__ deg,
                                                 int* __restrict__ bsum) {
    __shared__ int red[256];
    int t = threadIdx.x;
    int i = blockIdx.x * 256 + t;
    red[t] = (i < NNODES) ? deg[i] : 0;
    __syncthreads();
    for (int off = 128; off > 0; off >>= 1) {
        if (t < off) red[t] += red[t + off];
        __syncthreads();
    }
    if (t == 0) bsum[blockIdx.x] = red[0];
}

__global__ __launch_bounds__(256) void scan_base(const int* __restrict__ bsum,
                                                 int* __restrict__ bbase) {
    __shared__ int s[256];
    int t = threadIdx.x;
    int v = (t < NSB) ? bsum[t] : 0;
    s[t] = v;
    __syncthreads();
    for (int off = 1; off < 256; off <<= 1) {
        int u = (t >= off) ? s[t - off] : 0;
        __syncthreads();
        s[t] += u;
        __syncthreads();
    }
    if (t < NSB) bbase[t] = s[t] - v;  // exclusive
}

__global__ __launch_bounds__(256) void scan_fin(const int* __restrict__ deg,
                                                const int* __restrict__ bbase,
                                                int* __restrict__ rowptr,
                                                int* __restrict__ cursor) {
    __shared__ int s[256];
    int t = threadIdx.x;
    int i = blockIdx.x * 256 + t;
    int v = (i < NNODES) ? deg[i] : 0;
    s[t] = v;
    __syncthreads();
    for (int off = 1; off < 256; off <<= 1) {
        int u = (t >= off) ? s[t - off] : 0;
        __syncthreads();
        s[t] += u;
        __syncthreads();
    }
    int val = bbase[blockIdx.x] + s[t] - v;  // exclusive prefix
    if (i < NNODES) {
        rowptr[i] = val;
        cursor[i] = val;
    }
    if (i == NNODES) rowptr[i] = val;
}

__global__ __launch_bounds__(256) void fill_csr(const int* __restrict__ src,
                                                const int* __restrict__ dst,
                                                const float* __restrict__ ea,
                                                int* __restrict__ cursor,
                                                int4* __restrict__ epack) {
    int e = blockIdx.x * 256 + threadIdx.x;
    if (e >= NEDGES) return;
    int pos = atomicAdd(&cursor[dst[e]], 1);
    int4 v;
    v.x = src[e];
    v.y = __float_as_int(ea[e * 3 + 0]);
    v.z = __float_as_int(ea[e * 3 + 1]);
    v.w = __float_as_int(ea[e * 3 + 2]);
    epack[pos] = v;
}

// out[n] = x[n] + sum_{e in CSR[n]} relu(x[src_e] + ea_e @ We + be); all bf16 I/O.
__global__ __launch_bounds__(256) void agg_kernel(
    const unsigned short* __restrict__ xb, const int* __restrict__ rowptr,
    const int4* __restrict__ epack, const float* __restrict__ We,
    const float* __restrict__ be, unsigned short* __restrict__ out) {
    const int wave = threadIdx.x >> 6;
    const int lane = threadIdx.x & 63;
    const int n = blockIdx.x * 4 + wave;
    const int c = lane * 4;
    const float4 w0 = *reinterpret_cast<const float4*>(We + c);
    const float4 w1 = *reinterpret_cast<const float4*>(We + HD + c);
    const float4 w2 = *reinterpret_cast<const float4*>(We + 2 * HD + c);
    const float4 bb = *reinterpret_cast<const float4*>(be + c);
    ushort4 xv = *reinterpret_cast<const ushort4*>(xb + (size_t)n * HD + c);
    float4 acc = make_float4(b2f(xv.x), b2f(xv.y), b2f(xv.z), b2f(xv.w));
    int beg = rowptr[n], end = rowptr[n + 1];
    int4 ep = (beg < end) ? epack[beg] : make_int4(0, 0, 0, 0);
    for (int i = beg; i < end; ++i) {
        int4 e = ep;
        if (i + 1 < end) ep = epack[i + 1];
        float a0 = __int_as_float(e.y);
        float a1 = __int_as_float(e.z);
        float a2 = __int_as_float(e.w);
        ushort4 xs4 = *reinterpret_cast<const ushort4*>(xb + (size_t)e.x * HD + c);
        float sx = b2f(xs4.x), sy = b2f(xs4.y), sz = b2f(xs4.z), sw = b2f(xs4.w);
        acc.x += fmaxf(fmaf(a0, w0.x, fmaf(a1, w1.x, fmaf(a2, w2.x, sx + bb.x))), 0.f);
        acc.y += fmaxf(fmaf(a0, w0.y, fmaf(a1, w1.y, fmaf(a2, w2.y, sy + bb.y))), 0.f);
        acc.z += fmaxf(fmaf(a0, w0.z, fmaf(a1, w1.z, fmaf(a2, w2.z, sz + bb.z))), 0.f);
        acc.w += fmaxf(fmaf(a0, w0.w, fmaf(a1, w1.w, fmaf(a2, w2.w, sw + bb.w))), 0.f);
    }
    ushort4 o;
    o.x = (unsigned short)f2bf(acc.x);
    o.y = (unsigned short)f2bf(acc.y);
    o.z = (unsigned short)f2bf(acc.z);
    o.w = (unsigned short)f2bf(acc.w);
    *reinterpret_cast<ushort4*>(out + (size_t)n * HD + c) = o;
}

// Pack 11 HxH fp32 matrices into bf16 MFMA B-fragment order.
__global__ void pack_w(const float* __restrict__ Wm, const float* __restrict__ pW1,
                       const float* __restrict__ pW2, unsigned short* __restrict__ Wpk) {
    int g = blockIdx.x * 256 + threadIdx.x;  // 11 * 65536
    int mat = g >> 16;
    int r = g & 65535;
    int j = r & 7, lane = (r >> 3) & 63, kb = (r >> 9) & 7, ct = r >> 12;
    int k = kb * 32 + ((lane >> 4) << 3) + j;
    int c = ct * 16 + (lane & 15);
    const float* s = (mat < 9) ? (Wm + (size_t)mat * 65536)
                               : ((mat == 9) ? pW1 : pW2);
    Wpk[g] = (unsigned short)f2bf(s[k * 256 + c]);
}

// Fused NPH-linear chain over a resident 64-row tile.
// Phases 0..NPH-2: v = relu(acc+bias), written back to the LDS A-tile.
// Last phase: v = (RELU_LAST? relu : id)(acc+bias) (+res), stored bf16 or f32.
template <int NPH, bool RELU_LAST, bool RES, bool OUTF32>
__global__ __launch_bounds__(256) void gemm_fused(
    const unsigned short* __restrict__ A, const unsigned short* __restrict__ Wpk,
    const float* __restrict__ b0, const float* __restrict__ b1,
    const float* __restrict__ b2, const unsigned short* __restrict__ res,
    void* __restrict__ outv) {
    __shared__ __align__(16) unsigned char lds[64 * 512];
    const int tid = threadIdx.x;
    const int rbase = blockIdx.x * 64;

    for (int it = 0; it < 16; ++it) {
        int q = tid + it * 256;
        int row = q >> 6;
        int k4 = q & 63;
        int grow = rbase + row;
        uint2 v = make_uint2(0u, 0u);
        if (grow < NNODES)
            v = *reinterpret_cast<const uint2*>(A + (size_t)grow * HD + k4 * 4);
        int off = row * 512 + ((k4 * 8) ^ ((row & 7) << 4));
        *reinterpret_cast<uint2*>(lds + off) = v;
    }
    __syncthreads();

    const int wave = tid >> 6;
    const int lane = tid & 63;
    const int lr = lane & 15;
    const int lg = lane >> 4;

#pragma unroll
    for (int ph = 0; ph < NPH; ++ph) {
        const unsigned short* Wp = Wpk + (size_t)ph * 65536;
        const float* bias = (ph == 0) ? b0 : ((ph == 1) ? b1 : b2);

        f32x4 acc[4][4];
#pragma unroll
        for (int rt = 0; rt < 4; ++rt)
#pragma unroll
            for (int ct = 0; ct < 4; ++ct) acc[rt][ct] = (f32x4){0.f, 0.f, 0.f, 0.f};

#pragma unroll
        for (int kb = 0; kb < 8; ++kb) {
            bf16x8 a[4], b[4];
#pragma unroll
            for (int rt = 0; rt < 4; ++rt) {
                int row = rt * 16 + lr;
                int kbyte = kb * 64 + lg * 16;
                int off = row * 512 + (kbyte ^ ((row & 7) << 4));
                a[rt] = *reinterpret_cast<const bf16x8*>(lds + off);
            }
#pragma unroll
            for (int ct = 0; ct < 4; ++ct) {
                const unsigned short* p =
                    Wp + ((size_t)(((wave * 4 + ct) * 8 + kb) * 64 + lane)) * 8;
                b[ct] = *reinterpret_cast<const bf16x8*>(p);
            }
#pragma unroll
            for (int rt = 0; rt < 4; ++rt)
#pragma unroll
                for (int ct = 0; ct < 4; ++ct)
                    acc[rt][ct] = __builtin_amdgcn_mfma_f32_16x16x32_bf16(
                        a[rt], b[ct], acc[rt][ct], 0, 0, 0);
        }

        if (ph < NPH - 1) {
            __syncthreads();  // all waves done reading this phase's tile
#pragma unroll
            for (int rt = 0; rt < 4; ++rt) {
#pragma unroll
                for (int ct = 0; ct < 4; ++ct) {
                    int c = wave * 64 + ct * 16 + lr;
                    float bv = bias[c];
#pragma unroll
                    for (int i = 0; i < 4; ++i) {
                        int row = rt * 16 + lg * 4 + i;
                        float v = fmaxf(acc[rt][ct][i] + bv, 0.f);
                        int off = row * 512 + ((2 * c) ^ ((row & 7) << 4));
                        *reinterpret_cast<unsigned short*>(lds + off) =
                            (unsigned short)f2bf(v);
                    }
                }
            }
            __syncthreads();
        } else {
#pragma unroll
            for (int rt = 0; rt < 4; ++rt) {
                int row0 = rbase + rt * 16 + lg * 4;
#pragma unroll
                for (int ct = 0; ct < 4; ++ct) {
                    int c = wave * 64 + ct * 16 + lr;
                    float bv = bias[c];
#pragma unroll
                    for (int i = 0; i < 4; ++i) {
                        int row = row0 + i;
                        if (row < NNODES) {
                            float v = acc[rt][ct][i] + bv;
                            if (RELU_LAST) v = fmaxf(v, 0.f);
                            if (RES) v += b2f(res[(size_t)row * HD + c]);
                            if (OUTF32)
                                reinterpret_cast<float*>(outv)[(size_t)row * HD + c] = v;
                            else
                                reinterpret_cast<unsigned short*>(
                                    outv)[(size_t)row * HD + c] =
                                    (unsigned short)f2bf(v);
                        }
                    }
                }
            }
        }
    }
}

extern "C" void kernel_launch(void* const* d_in, const int* in_sizes, int n_in,
                              void* d_out, int out_size, void* d_ws, size_t ws_size,
                              hipStream_t stream) {
    const float* x   = (const float*)d_in[0];
    const int*   ei  = (const int*)d_in[1];
    const float* ea  = (const float*)d_in[2];
    const float* We  = (const float*)d_in[3];
    const float* be  = (const float*)d_in[4];
    const float* Wm  = (const float*)d_in[5];
    const float* bm  = (const float*)d_in[6];
    const float* pW1 = (const float*)d_in[7];
    const float* pb1 = (const float*)d_in[8];
    const float* pW2 = (const float*)d_in[9];
    const float* pb2 = (const float*)d_in[10];
    float* out = (float*)d_out;

    const size_t NH = (size_t)NNODES * HD;
    unsigned short* xb   = (unsigned short*)d_ws;
    unsigned short* curb = xb + NH;
    unsigned short* aggb = curb + NH;
    unsigned short* Wpk  = aggb + NH;           // 11*65536 shorts
    int* rowptr = (int*)(Wpk + 11 * 65536);     // NNODES+1
    int* cursor = rowptr + 50004;
    int* deg    = cursor + 50004;
    int* bsum   = deg + 50004;                  // NSB
    int* bbase  = bsum + 256;
    int4* epack = (int4*)d_out;  // scratch until the head kernel writes d_out

    const int* srcI = ei;
    const int* dstI = ei + NEDGES;

    // --- One-time prep ---
    x2bf<<<dim3(NH / 4 / 256), dim3(256), 0, stream>>>(x, xb);
    zero_int<<<dim3((NNODES + 255) / 256), dim3(256), 0, stream>>>(deg, NNODES);
    pack_w<<<dim3(11 * 65536 / 256), dim3(256), 0, stream>>>(Wm, pW1, pW2, Wpk);
    hist_kernel<<<dim3((NEDGES + 255) / 256), dim3(256), 0, stream>>>(dstI, deg);
    scan_part<<<dim3(NSB), dim3(256), 0, stream>>>(deg, bsum);
    scan_base<<<dim3(1), dim3(256), 0, stream>>>(bsum, bbase);
    scan_fin<<<dim3(NSB), dim3(256), 0, stream>>>(deg, bbase, rowptr, cursor);
    fill_csr<<<dim3((NEDGES + 255) / 256), dim3(256), 0, stream>>>(srcI, dstI, ea,
                                                                   cursor, epack);

    const int gemm_grid = (NNODES + 63) / 64;
    for (int l = 0; l < 3; ++l) {
        const unsigned short* xin = (l == 0) ? xb : curb;
        agg_kernel<<<dim3(NNODES / 4), dim3(256), 0, stream>>>(
            xin, rowptr, epack, We + (size_t)l * 3 * HD, be + (size_t)l * HD, aggb);
        gemm_fused<3, true, true, false><<<dim3(gemm_grid), dim3(256), 0, stream>>>(
            aggb, Wpk + (size_t)l * 3 * 65536, bm + (size_t)(l * 3 + 0) * HD,
            bm + (size_t)(l * 3 + 1) * HD, bm + (size_t)(l * 3 + 2) * HD, xin, curb);
    }
    gemm_fused<2, false, false, true><<<dim3(gemm_grid), dim3(256), 0, stream>>>(
        curb, Wpk + (size_t)9 * 65536, pb1, pb2, nullptr, nullptr, out);
}

// Round 5
// 707.189 us; speedup vs baseline: 11.9932x; 1.0854x over previous
//
#include <hip/hip_runtime.h>

#define NNODES 50000
#define NEDGES 800000
#define HD 256
#define NSB 196  // scan blocks: 196*256 = 50176 >= NNODES+1

typedef __attribute__((ext_vector_type(8))) short bf16x8;
typedef __attribute__((ext_vector_type(4))) float f32x4;

__device__ __forceinline__ unsigned int f2bf(float f) {
    union { float f; unsigned int u; } v; v.f = f;
    unsigned int u = v.u;
    u += 0x7fffu + ((u >> 16) & 1u);
    return u >> 16;
}
__device__ __forceinline__ float b2f(unsigned short u) {
    union { unsigned int u; float f; } v; v.u = ((unsigned int)u) << 16;
    return v.f;
}

__global__ void zero_int(int* __restrict__ p, int n) {
    int i = blockIdx.x * blockDim.x + threadIdx.x;
    if (i < n) p[i] = 0;
}

__global__ __launch_bounds__(256) void x2bf(const float* __restrict__ x,
                                            unsigned short* __restrict__ xb) {
    int i = blockIdx.x * 256 + threadIdx.x;
    float4 v = reinterpret_cast<const float4*>(x)[i];
    ushort4 o;
    o.x = (unsigned short)f2bf(v.x);
    o.y = (unsigned short)f2bf(v.y);
    o.z = (unsigned short)f2bf(v.z);
    o.w = (unsigned short)f2bf(v.w);
    reinterpret_cast<ushort4*>(xb)[i] = o;
}

__global__ __launch_bounds__(256) void hist_kernel(const int* __restrict__ dst,
                                                   int* __restrict__ deg) {
    int e = blockIdx.x * 256 + threadIdx.x;
    if (e < NEDGES) atomicAdd(&deg[dst[e]], 1);
}

// --- 3-kernel exclusive scan of deg[0..NNODES) ---
__global__ __launch_bounds__(256) void scan_part(const int* __restrict__ deg,
                                                 int* __restrict__ bsum) {
    __shared__ int red[256];
    int t = threadIdx.x;
    int i = blockIdx.x * 256 + t;
    red[t] = (i < NNODES) ? deg[i] : 0;
    __syncthreads();
    for (int off = 128; off > 0; off >>= 1) {
        if (t < off) red[t] += red[t + off];
        __syncthreads();
    }
    if (t == 0) bsum[blockIdx.x] = red[0];
}

__global__ __launch_bounds__(256) void scan_base(const int* __restrict__ bsum,
                                                 int* __restrict__ bbase) {
    __shared__ int s[256];
    int t = threadIdx.x;
    int v = (t < NSB) ? bsum[t] : 0;
    s[t] = v;
    __syncthreads();
    for (int off = 1; off < 256; off <<= 1) {
        int u = (t >= off) ? s[t - off] : 0;
        __syncthreads();
        s[t] += u;
        __syncthreads();
    }
    if (t < NSB) bbase[t] = s[t] - v;  // exclusive
}

__global__ __launch_bounds__(256) void scan_fin(const int* __restrict__ deg,
                                                const int* __restrict__ bbase,
                                                int* __restrict__ rowptr,
                                                int* __restrict__ cursor) {
    __shared__ int s[256];
    int t = threadIdx.x;
    int i = blockIdx.x * 256 + t;
    int v = (i < NNODES) ? deg[i] : 0;
    s[t] = v;
    __syncthreads();
    for (int off = 1; off < 256; off <<= 1) {
        int u = (t >= off) ? s[t - off] : 0;
        __syncthreads();
        s[t] += u;
        __syncthreads();
    }
    int val = bbase[blockIdx.x] + s[t] - v;  // exclusive prefix
    if (i < NNODES) {
        rowptr[i] = val;
        cursor[i] = val;
    }
    if (i == NNODES) rowptr[i] = val;
}

__global__ __launch_bounds__(256) void fill_csr(const int* __restrict__ src,
                                                const int* __restrict__ dst,
                                                const float* __restrict__ ea,
                                                int* __restrict__ cursor,
                                                int4* __restrict__ epack) {
    int e = blockIdx.x * 256 + threadIdx.x;
    if (e >= NEDGES) return;
    int pos = atomicAdd(&cursor[dst[e]], 1);
    int4 v;
    v.x = src[e];
    v.y = __float_as_int(ea[e * 3 + 0]);
    v.z = __float_as_int(ea[e * 3 + 1]);
    v.w = __float_as_int(ea[e * 3 + 2]);
    epack[pos] = v;
}

// out[n] = x[n] + sum_{e in CSR[n]} relu(x[src_e] + ea_e @ We + be); all bf16 I/O.
__global__ __launch_bounds__(256) void agg_kernel(
    const unsigned short* __restrict__ xb, const int* __restrict__ rowptr,
    const int4* __restrict__ epack, const float* __restrict__ We,
    const float* __restrict__ be, unsigned short* __restrict__ out) {
    const int wave = threadIdx.x >> 6;
    const int lane = threadIdx.x & 63;
    const int n = blockIdx.x * 4 + wave;
    const int c = lane * 4;
    const float4 w0 = *reinterpret_cast<const float4*>(We + c);
    const float4 w1 = *reinterpret_cast<const float4*>(We + HD + c);
    const float4 w2 = *reinterpret_cast<const float4*>(We + 2 * HD + c);
    const float4 bb = *reinterpret_cast<const float4*>(be + c);
    ushort4 xv = *reinterpret_cast<const ushort4*>(xb + (size_t)n * HD + c);
    float4 acc = make_float4(b2f(xv.x), b2f(xv.y), b2f(xv.z), b2f(xv.w));
    int beg = rowptr[n], end = rowptr[n + 1];
    int4 ep = (beg < end) ? epack[beg] : make_int4(0, 0, 0, 0);
    for (int i = beg; i < end; ++i) {
        int4 e = ep;
        if (i + 1 < end) ep = epack[i + 1];
        float a0 = __int_as_float(e.y);
        float a1 = __int_as_float(e.z);
        float a2 = __int_as_float(e.w);
        ushort4 xs4 = *reinterpret_cast<const ushort4*>(xb + (size_t)e.x * HD + c);
        float sx = b2f(xs4.x), sy = b2f(xs4.y), sz = b2f(xs4.z), sw = b2f(xs4.w);
        acc.x += fmaxf(fmaf(a0, w0.x, fmaf(a1, w1.x, fmaf(a2, w2.x, sx + bb.x))), 0.f);
        acc.y += fmaxf(fmaf(a0, w0.y, fmaf(a1, w1.y, fmaf(a2, w2.y, sy + bb.y))), 0.f);
        acc.z += fmaxf(fmaf(a0, w0.z, fmaf(a1, w1.z, fmaf(a2, w2.z, sz + bb.z))), 0.f);
        acc.w += fmaxf(fmaf(a0, w0.w, fmaf(a1, w1.w, fmaf(a2, w2.w, sw + bb.w))), 0.f);
    }
    ushort4 o;
    o.x = (unsigned short)f2bf(acc.x);
    o.y = (unsigned short)f2bf(acc.y);
    o.z = (unsigned short)f2bf(acc.z);
    o.w = (unsigned short)f2bf(acc.w);
    *reinterpret_cast<ushort4*>(out + (size_t)n * HD + c) = o;
}

// Pack 11 HxH fp32 matrices into bf16 MFMA B-fragment order.
__global__ void pack_w(const float* __restrict__ Wm, const float* __restrict__ pW1,
                       const float* __restrict__ pW2, unsigned short* __restrict__ Wpk) {
    int g = blockIdx.x * 256 + threadIdx.x;  // 11 * 65536
    int mat = g >> 16;
    int r = g & 65535;
    int j = r & 7, lane = (r >> 3) & 63, kb = (r >> 9) & 7, ct = r >> 12;
    int k = kb * 32 + ((lane >> 4) << 3) + j;
    int c = ct * 16 + (lane & 15);
    const float* s = (mat < 9) ? (Wm + (size_t)mat * 65536)
                               : ((mat == 9) ? pW1 : pW2);
    Wpk[g] = (unsigned short)f2bf(s[k * 256 + c]);
}

// Fused NPH-linear chain over a resident 64-row tile.
// Whole-phase B preload (32x global_load_dwordx4 into 128 VGPRs) hides L2
// latency; phase-0 preload overlaps the A-staging barrier.
template <int NPH, bool RELU_LAST, bool RES, bool OUTF32>
__global__ __launch_bounds__(256, 2) void gemm_fused(
    const unsigned short* __restrict__ A, const unsigned short* __restrict__ Wpk,
    const float* __restrict__ b0, const float* __restrict__ b1,
    const float* __restrict__ b2, const unsigned short* __restrict__ res,
    void* __restrict__ outv) {
    __shared__ __align__(16) unsigned char lds[64 * 512];
    const int tid = threadIdx.x;
    const int rbase = blockIdx.x * 64;
    const int wave = tid >> 6;
    const int lane = tid & 63;
    const int lr = lane & 15;
    const int lg = lane >> 4;

    // Issue phase-0 B preload first: latency overlaps A staging + barrier.
    bf16x8 b[8][4];
#pragma unroll
    for (int kb = 0; kb < 8; ++kb)
#pragma unroll
        for (int ct = 0; ct < 4; ++ct)
            b[kb][ct] = *reinterpret_cast<const bf16x8*>(
                Wpk + ((size_t)(((wave * 4 + ct) * 8 + kb) * 64 + lane)) * 8);

    for (int it = 0; it < 16; ++it) {
        int q = tid + it * 256;
        int row = q >> 6;
        int k4 = q & 63;
        int grow = rbase + row;
        uint2 v = make_uint2(0u, 0u);
        if (grow < NNODES)
            v = *reinterpret_cast<const uint2*>(A + (size_t)grow * HD + k4 * 4);
        int off = row * 512 + ((k4 * 8) ^ ((row & 7) << 4));
        *reinterpret_cast<uint2*>(lds + off) = v;
    }
    __syncthreads();

#pragma unroll
    for (int ph = 0; ph < NPH; ++ph) {
        const float* bias = (ph == 0) ? b0 : ((ph == 1) ? b1 : b2);

        f32x4 acc[4][4];
#pragma unroll
        for (int rt = 0; rt < 4; ++rt)
#pragma unroll
            for (int ct = 0; ct < 4; ++ct) acc[rt][ct] = (f32x4){0.f, 0.f, 0.f, 0.f};

#pragma unroll
        for (int kb = 0; kb < 8; ++kb) {
            bf16x8 a[4];
#pragma unroll
            for (int rt = 0; rt < 4; ++rt) {
                int row = rt * 16 + lr;
                int kbyte = kb * 64 + lg * 16;
                int off = row * 512 + (kbyte ^ ((row & 7) << 4));
                a[rt] = *reinterpret_cast<const bf16x8*>(lds + off);
            }
#pragma unroll
            for (int rt = 0; rt < 4; ++rt)
#pragma unroll
                for (int ct = 0; ct < 4; ++ct)
                    acc[rt][ct] = __builtin_amdgcn_mfma_f32_16x16x32_bf16(
                        a[rt], b[kb][ct], acc[rt][ct], 0, 0, 0);
        }

        if (ph < NPH - 1) {
            __syncthreads();  // all waves done reading this phase's tile
#pragma unroll
            for (int rt = 0; rt < 4; ++rt) {
#pragma unroll
                for (int ct = 0; ct < 4; ++ct) {
                    int c = wave * 64 + ct * 16 + lr;
                    float bv = bias[c];
#pragma unroll
                    for (int i = 0; i < 4; ++i) {
                        int row = rt * 16 + lg * 4 + i;
                        float v = fmaxf(acc[rt][ct][i] + bv, 0.f);
                        int off = row * 512 + ((2 * c) ^ ((row & 7) << 4));
                        *reinterpret_cast<unsigned short*>(lds + off) =
                            (unsigned short)f2bf(v);
                    }
                }
            }
            // Preload next phase's B while waiting at the barrier.
            const unsigned short* Wn = Wpk + (size_t)(ph + 1) * 65536;
#pragma unroll
            for (int kb = 0; kb < 8; ++kb)
#pragma unroll
                for (int ct = 0; ct < 4; ++ct)
                    b[kb][ct] = *reinterpret_cast<const bf16x8*>(
                        Wn + ((size_t)(((wave * 4 + ct) * 8 + kb) * 64 + lane)) * 8);
            __syncthreads();
        } else {
#pragma unroll
            for (int rt = 0; rt < 4; ++rt) {
                int row0 = rbase + rt * 16 + lg * 4;
#pragma unroll
                for (int ct = 0; ct < 4; ++ct) {
                    int c = wave * 64 + ct * 16 + lr;
                    float bv = bias[c];
#pragma unroll
                    for (int i = 0; i < 4; ++i) {
                        int row = row0 + i;
                        if (row < NNODES) {
                            float v = acc[rt][ct][i] + bv;
                            if (RELU_LAST) v = fmaxf(v, 0.f);
                            if (RES) v += b2f(res[(size_t)row * HD + c]);
                            if (OUTF32)
                                reinterpret_cast<float*>(outv)[(size_t)row * HD + c] = v;
                            else
                                reinterpret_cast<unsigned short*>(
                                    outv)[(size_t)row * HD + c] =
                                    (unsigned short)f2bf(v);
                        }
                    }
                }
            }
        }
    }
}

extern "C" void kernel_launch(void* const* d_in, const int* in_sizes, int n_in,
                              void* d_out, int out_size, void* d_ws, size_t ws_size,
                              hipStream_t stream) {
    const float* x   = (const float*)d_in[0];
    const int*   ei  = (const int*)d_in[1];
    const float* ea  = (const float*)d_in[2];
    const float* We  = (const float*)d_in[3];
    const float* be  = (const float*)d_in[4];
    const float* Wm  = (const float*)d_in[5];
    const float* bm  = (const float*)d_in[6];
    const float* pW1 = (const float*)d_in[7];
    const float* pb1 = (const float*)d_in[8];
    const float* pW2 = (const float*)d_in[9];
    const float* pb2 = (const float*)d_in[10];
    float* out = (float*)d_out;

    const size_t NH = (size_t)NNODES * HD;
    unsigned short* xb   = (unsigned short*)d_ws;
    unsigned short* curb = xb + NH;
    unsigned short* aggb = curb + NH;
    unsigned short* Wpk  = aggb + NH;           // 11*65536 shorts
    int* rowptr = (int*)(Wpk + 11 * 65536);     // NNODES+1
    int* cursor = rowptr + 50004;
    int* deg    = cursor + 50004;
    int* bsum   = deg + 50004;                  // NSB
    int* bbase  = bsum + 256;
    int4* epack = (int4*)d_out;  // scratch until the head kernel writes d_out

    const int* srcI = ei;
    const int* dstI = ei + NEDGES;

    // --- One-time prep ---
    x2bf<<<dim3(NH / 4 / 256), dim3(256), 0, stream>>>(x, xb);
    zero_int<<<dim3((NNODES + 255) / 256), dim3(256), 0, stream>>>(deg, NNODES);
    pack_w<<<dim3(11 * 65536 / 256), dim3(256), 0, stream>>>(Wm, pW1, pW2, Wpk);
    hist_kernel<<<dim3((NEDGES + 255) / 256), dim3(256), 0, stream>>>(dstI, deg);
    scan_part<<<dim3(NSB), dim3(256), 0, stream>>>(deg, bsum);
    scan_base<<<dim3(1), dim3(256), 0, stream>>>(bsum, bbase);
    scan_fin<<<dim3(NSB), dim3(256), 0, stream>>>(deg, bbase, rowptr, cursor);
    fill_csr<<<dim3((NEDGES + 255) / 256), dim3(256), 0, stream>>>(srcI, dstI, ea,
                                                                   cursor, epack);

    const int gemm_grid = (NNODES + 63) / 64;
    for (int l = 0; l < 3; ++l) {
        const unsigned short* xin = (l == 0) ? xb : curb;
        agg_kernel<<<dim3(NNODES / 4), dim3(256), 0, stream>>>(
            xin, rowptr, epack, We + (size_t)l * 3 * HD, be + (size_t)l * HD, aggb);
        gemm_fused<3, true, true, false><<<dim3(gemm_grid), dim3(256), 0, stream>>>(
            aggb, Wpk + (size_t)l * 3 * 65536, bm + (size_t)(l * 3 + 0) * HD,
            bm + (size_t)(l * 3 + 1) * HD, bm + (size_t)(l * 3 + 2) * HD, xin, curb);
    }
    gemm_fused<2, false, false, true><<<dim3(gemm_grid), dim3(256), 0, stream>>>(
        curb, Wpk + (size_t)9 * 65536, pb1, pb2, nullptr, nullptr, out);
}

// Round 6
// 644.883 us; speedup vs baseline: 13.1519x; 1.0966x over previous
//
#include <hip/hip_runtime.h>

#define NNODES 50000
#define NEDGES 800000
#define HD 256
#define NSB 196  // scan blocks: 196*256 = 50176 >= NNODES+1

typedef __attribute__((ext_vector_type(8))) short bf16x8;
typedef __attribute__((ext_vector_type(4))) float f32x4;

__device__ __forceinline__ unsigned int f2bf(float f) {
    union { float f; unsigned int u; } v; v.f = f;
    unsigned int u = v.u;
    u += 0x7fffu + ((u >> 16) & 1u);
    return u >> 16;
}
__device__ __forceinline__ float b2f(unsigned short u) {
    union { unsigned int u; float f; } v; v.u = ((unsigned int)u) << 16;
    return v.f;
}

__global__ void zero_int(int* __restrict__ p, int n) {
    int i = blockIdx.x * blockDim.x + threadIdx.x;
    if (i < n) p[i] = 0;
}

__global__ __launch_bounds__(256) void x2bf(const float* __restrict__ x,
                                            unsigned short* __restrict__ xb) {
    int i = blockIdx.x * 256 + threadIdx.x;
    float4 v = reinterpret_cast<const float4*>(x)[i];
    ushort4 o;
    o.x = (unsigned short)f2bf(v.x);
    o.y = (unsigned short)f2bf(v.y);
    o.z = (unsigned short)f2bf(v.z);
    o.w = (unsigned short)f2bf(v.w);
    reinterpret_cast<ushort4*>(xb)[i] = o;
}

__global__ __launch_bounds__(256) void hist_kernel(const int* __restrict__ dst,
                                                   int* __restrict__ deg) {
    int e = blockIdx.x * 256 + threadIdx.x;
    if (e < NEDGES) atomicAdd(&deg[dst[e]], 1);
}

// --- 3-kernel exclusive scan of deg[0..NNODES) ---
__global__ __launch_bounds__(256) void scan_part(const int* __restrict__ deg,
                                                 int* __restrict__ bsum) {
    __shared__ int red[256];
    int t = threadIdx.x;
    int i = blockIdx.x * 256 + t;
    red[t] = (i < NNODES) ? deg[i] : 0;
    __syncthreads();
    for (int off = 128; off > 0; off >>= 1) {
        if (t < off) red[t] += red[t + off];
        __syncthreads();
    }
    if (t == 0) bsum[blockIdx.x] = red[0];
}

__global__ __launch_bounds__(256) void scan_base(const int* __restrict__ bsum,
                                                 int* __restrict__ bbase) {
    __shared__ int s[256];
    int t = threadIdx.x;
    int v = (t < NSB) ? bsum[t] : 0;
    s[t] = v;
    __syncthreads();
    for (int off = 1; off < 256; off <<= 1) {
        int u = (t >= off) ? s[t - off] : 0;
        __syncthreads();
        s[t] += u;
        __syncthreads();
    }
    if (t < NSB) bbase[t] = s[t] - v;  // exclusive
}

__global__ __launch_bounds__(256) void scan_fin(const int* __restrict__ deg,
                                                const int* __restrict__ bbase,
                                                int* __restrict__ rowptr,
                                                int* __restrict__ cursor) {
    __shared__ int s[256];
    int t = threadIdx.x;
    int i = blockIdx.x * 256 + t;
    int v = (i < NNODES) ? deg[i] : 0;
    s[t] = v;
    __syncthreads();
    for (int off = 1; off < 256; off <<= 1) {
        int u = (t >= off) ? s[t - off] : 0;
        __syncthreads();
        s[t] += u;
        __syncthreads();
    }
    int val = bbase[blockIdx.x] + s[t] - v;  // exclusive prefix
    if (i < NNODES) {
        rowptr[i] = val;
        cursor[i] = val;
    }
    if (i == NNODES) rowptr[i] = val;
}

__global__ __launch_bounds__(256) void fill_csr(const int* __restrict__ src,
                                                const int* __restrict__ dst,
                                                const float* __restrict__ ea,
                                                int* __restrict__ cursor,
                                                int4* __restrict__ epack) {
    int e = blockIdx.x * 256 + threadIdx.x;
    if (e >= NEDGES) return;
    int pos = atomicAdd(&cursor[dst[e]], 1);
    int4 v;
    v.x = src[e];
    v.y = __float_as_int(ea[e * 3 + 0]);
    v.z = __float_as_int(ea[e * 3 + 1]);
    v.w = __float_as_int(ea[e * 3 + 2]);
    epack[pos] = v;
}

// out[n] = x[n] + sum_{e in CSR[n]} relu(x[src_e] + ea_e @ We + be); all bf16 I/O.
__global__ __launch_bounds__(256) void agg_kernel(
    const unsigned short* __restrict__ xb, const int* __restrict__ rowptr,
    const int4* __restrict__ epack, const float* __restrict__ We,
    const float* __restrict__ be, unsigned short* __restrict__ out) {
    const int wave = threadIdx.x >> 6;
    const int lane = threadIdx.x & 63;
    const int n = blockIdx.x * 4 + wave;
    const int c = lane * 4;
    const float4 w0 = *reinterpret_cast<const float4*>(We + c);
    const float4 w1 = *reinterpret_cast<const float4*>(We + HD + c);
    const float4 w2 = *reinterpret_cast<const float4*>(We + 2 * HD + c);
    const float4 bb = *reinterpret_cast<const float4*>(be + c);
    ushort4 xv = *reinterpret_cast<const ushort4*>(xb + (size_t)n * HD + c);
    float4 acc = make_float4(b2f(xv.x), b2f(xv.y), b2f(xv.z), b2f(xv.w));
    int beg = rowptr[n], end = rowptr[n + 1];
    int4 ep = (beg < end) ? epack[beg] : make_int4(0, 0, 0, 0);
    for (int i = beg; i < end; ++i) {
        int4 e = ep;
        if (i + 1 < end) ep = epack[i + 1];
        float a0 = __int_as_float(e.y);
        float a1 = __int_as_float(e.z);
        float a2 = __int_as_float(e.w);
        ushort4 xs4 = *reinterpret_cast<const ushort4*>(xb + (size_t)e.x * HD + c);
        float sx = b2f(xs4.x), sy = b2f(xs4.y), sz = b2f(xs4.z), sw = b2f(xs4.w);
        acc.x += fmaxf(fmaf(a0, w0.x, fmaf(a1, w1.x, fmaf(a2, w2.x, sx + bb.x))), 0.f);
        acc.y += fmaxf(fmaf(a0, w0.y, fmaf(a1, w1.y, fmaf(a2, w2.y, sy + bb.y))), 0.f);
        acc.z += fmaxf(fmaf(a0, w0.z, fmaf(a1, w1.z, fmaf(a2, w2.z, sz + bb.z))), 0.f);
        acc.w += fmaxf(fmaf(a0, w0.w, fmaf(a1, w1.w, fmaf(a2, w2.w, sw + bb.w))), 0.f);
    }
    ushort4 o;
    o.x = (unsigned short)f2bf(acc.x);
    o.y = (unsigned short)f2bf(acc.y);
    o.z = (unsigned short)f2bf(acc.z);
    o.w = (unsigned short)f2bf(acc.w);
    *reinterpret_cast<ushort4*>(out + (size_t)n * HD + c) = o;
}

// Pack 11 HxH fp32 matrices into bf16 MFMA B-fragment order.
__global__ void pack_w(const float* __restrict__ Wm, const float* __restrict__ pW1,
                       const float* __restrict__ pW2, unsigned short* __restrict__ Wpk) {
    int g = blockIdx.x * 256 + threadIdx.x;  // 11 * 65536
    int mat = g >> 16;
    int r = g & 65535;
    int j = r & 7, lane = (r >> 3) & 63, kb = (r >> 9) & 7, ct = r >> 12;
    int k = kb * 32 + ((lane >> 4) << 3) + j;
    int c = ct * 16 + (lane & 15);
    const float* s = (mat < 9) ? (Wm + (size_t)mat * 65536)
                               : ((mat == 9) ? pW1 : pW2);
    Wpk[g] = (unsigned short)f2bf(s[k * 256 + c]);
}

// Load the 4 B-fragments of one kb-step (64B/lane total).
__device__ __forceinline__ void load_b(const unsigned short* __restrict__ Wp,
                                       int wave, int lane, int kb, bf16x8* dst) {
#pragma unroll
    for (int ct = 0; ct < 4; ++ct)
        dst[ct] = *reinterpret_cast<const bf16x8*>(
            Wp + ((size_t)(((wave * 4 + ct) * 8 + kb) * 64 + lane)) * 8);
}

// Fused NPH-linear chain over a resident 64-row tile.
// B comes through a ring-3 register pipeline (48 VGPRs): at step kb we issue
// kb+2's loads and MFMA on buf[kb%3] -- ~2 kb-steps of MFMA cover L2 latency
// without spilling (round-5 lesson: whole-phase preload = 128 VGPRs = scratch).
template <int NPH, bool RELU_LAST, bool RES, bool OUTF32>
__global__ __launch_bounds__(256, 2) void gemm_fused(
    const unsigned short* __restrict__ A, const unsigned short* __restrict__ Wpk,
    const float* __restrict__ b0, const float* __restrict__ b1,
    const float* __restrict__ b2, const unsigned short* __restrict__ res,
    void* __restrict__ outv) {
    __shared__ __align__(16) unsigned char lds[64 * 512];
    const int tid = threadIdx.x;
    const int rbase = blockIdx.x * 64;
    const int wave = tid >> 6;
    const int lane = tid & 63;
    const int lr = lane & 15;
    const int lg = lane >> 4;

    // Prime the ring for phase 0 before staging: latency overlaps A loads.
    bf16x8 bb[3][4];
    load_b(Wpk, wave, lane, 0, bb[0]);
    load_b(Wpk, wave, lane, 1, bb[1]);

    for (int it = 0; it < 16; ++it) {
        int q = tid + it * 256;
        int row = q >> 6;
        int k4 = q & 63;
        int grow = rbase + row;
        uint2 v = make_uint2(0u, 0u);
        if (grow < NNODES)
            v = *reinterpret_cast<const uint2*>(A + (size_t)grow * HD + k4 * 4);
        int off = row * 512 + ((k4 * 8) ^ ((row & 7) << 4));
        *reinterpret_cast<uint2*>(lds + off) = v;
    }
    __syncthreads();

#pragma unroll
    for (int ph = 0; ph < NPH; ++ph) {
        const unsigned short* Wp = Wpk + (size_t)ph * 65536;
        const float* bias = (ph == 0) ? b0 : ((ph == 1) ? b1 : b2);

        f32x4 acc[4][4];
#pragma unroll
        for (int rt = 0; rt < 4; ++rt)
#pragma unroll
            for (int ct = 0; ct < 4; ++ct) acc[rt][ct] = (f32x4){0.f, 0.f, 0.f, 0.f};

#pragma unroll
        for (int kb = 0; kb < 8; ++kb) {
            if (kb + 2 < 8) load_b(Wp, wave, lane, kb + 2, bb[(kb + 2) % 3]);
            bf16x8 a[4];
#pragma unroll
            for (int rt = 0; rt < 4; ++rt) {
                int row = rt * 16 + lr;
                int kbyte = kb * 64 + lg * 16;
                int off = row * 512 + (kbyte ^ ((row & 7) << 4));
                a[rt] = *reinterpret_cast<const bf16x8*>(lds + off);
            }
#pragma unroll
            for (int rt = 0; rt < 4; ++rt)
#pragma unroll
                for (int ct = 0; ct < 4; ++ct)
                    acc[rt][ct] = __builtin_amdgcn_mfma_f32_16x16x32_bf16(
                        a[rt], bb[kb % 3][ct], acc[rt][ct], 0, 0, 0);
        }

        if (ph < NPH - 1) {
            __syncthreads();  // all waves done reading this phase's tile
#pragma unroll
            for (int rt = 0; rt < 4; ++rt) {
#pragma unroll
                for (int ct = 0; ct < 4; ++ct) {
                    int c = wave * 64 + ct * 16 + lr;
                    float bv = bias[c];
#pragma unroll
                    for (int i = 0; i < 4; ++i) {
                        int row = rt * 16 + lg * 4 + i;
                        float v = fmaxf(acc[rt][ct][i] + bv, 0.f);
                        int off = row * 512 + ((2 * c) ^ ((row & 7) << 4));
                        *reinterpret_cast<unsigned short*>(lds + off) =
                            (unsigned short)f2bf(v);
                    }
                }
            }
            // Prime the ring for the next phase while waiting at the barrier.
            const unsigned short* Wn = Wpk + (size_t)(ph + 1) * 65536;
            load_b(Wn, wave, lane, 0, bb[0]);
            load_b(Wn, wave, lane, 1, bb[1]);
            __syncthreads();
        } else {
#pragma unroll
            for (int rt = 0; rt < 4; ++rt) {
                int row0 = rbase + rt * 16 + lg * 4;
#pragma unroll
                for (int ct = 0; ct < 4; ++ct) {
                    int c = wave * 64 + ct * 16 + lr;
                    float bv = bias[c];
#pragma unroll
                    for (int i = 0; i < 4; ++i) {
                        int row = row0 + i;
                        if (row < NNODES) {
                            float v = acc[rt][ct][i] + bv;
                            if (RELU_LAST) v = fmaxf(v, 0.f);
                            if (RES) v += b2f(res[(size_t)row * HD + c]);
                            if (OUTF32)
                                reinterpret_cast<float*>(outv)[(size_t)row * HD + c] = v;
                            else
                                reinterpret_cast<unsigned short*>(
                                    outv)[(size_t)row * HD + c] =
                                    (unsigned short)f2bf(v);
                        }
                    }
                }
            }
        }
    }
}

extern "C" void kernel_launch(void* const* d_in, const int* in_sizes, int n_in,
                              void* d_out, int out_size, void* d_ws, size_t ws_size,
                              hipStream_t stream) {
    const float* x   = (const float*)d_in[0];
    const int*   ei  = (const int*)d_in[1];
    const float* ea  = (const float*)d_in[2];
    const float* We  = (const float*)d_in[3];
    const float* be  = (const float*)d_in[4];
    const float* Wm  = (const float*)d_in[5];
    const float* bm  = (const float*)d_in[6];
    const float* pW1 = (const float*)d_in[7];
    const float* pb1 = (const float*)d_in[8];
    const float* pW2 = (const float*)d_in[9];
    const float* pb2 = (const float*)d_in[10];
    float* out = (float*)d_out;

    const size_t NH = (size_t)NNODES * HD;
    unsigned short* xb   = (unsigned short*)d_ws;
    unsigned short* curb = xb + NH;
    unsigned short* aggb = curb + NH;
    unsigned short* Wpk  = aggb + NH;           // 11*65536 shorts
    int* rowptr = (int*)(Wpk + 11 * 65536);     // NNODES+1
    int* cursor = rowptr + 50004;
    int* deg    = cursor + 50004;
    int* bsum   = deg + 50004;                  // NSB
    int* bbase  = bsum + 256;
    int4* epack = (int4*)d_out;  // scratch until the head kernel writes d_out

    const int* srcI = ei;
    const int* dstI = ei + NEDGES;

    // --- One-time prep ---
    x2bf<<<dim3(NH / 4 / 256), dim3(256), 0, stream>>>(x, xb);
    zero_int<<<dim3((NNODES + 255) / 256), dim3(256), 0, stream>>>(deg, NNODES);
    pack_w<<<dim3(11 * 65536 / 256), dim3(256), 0, stream>>>(Wm, pW1, pW2, Wpk);
    hist_kernel<<<dim3((NEDGES + 255) / 256), dim3(256), 0, stream>>>(dstI, deg);
    scan_part<<<dim3(NSB), dim3(256), 0, stream>>>(deg, bsum);
    scan_base<<<dim3(1), dim3(256), 0, stream>>>(bsum, bbase);
    scan_fin<<<dim3(NSB), dim3(256), 0, stream>>>(deg, bbase, rowptr, cursor);
    fill_csr<<<dim3((NEDGES + 255) / 256), dim3(256), 0, stream>>>(srcI, dstI, ea,
                                                                   cursor, epack);

    const int gemm_grid = (NNODES + 63) / 64;
    for (int l = 0; l < 3; ++l) {
        const unsigned short* xin = (l == 0) ? xb : curb;
        agg_kernel<<<dim3(NNODES / 4), dim3(256), 0, stream>>>(
            xin, rowptr, epack, We + (size_t)l * 3 * HD, be + (size_t)l * HD, aggb);
        gemm_fused<3, true, true, false><<<dim3(gemm_grid), dim3(256), 0, stream>>>(
            aggb, Wpk + (size_t)l * 3 * 65536, bm + (size_t)(l * 3 + 0) * HD,
            bm + (size_t)(l * 3 + 1) * HD, bm + (size_t)(l * 3 + 2) * HD, xin, curb);
    }
    gemm_fused<2, false, false, true><<<dim3(gemm_grid), dim3(256), 0, stream>>>(
        curb, Wpk + (size_t)9 * 65536, pb1, pb2, nullptr, nullptr, out);
}

// Round 7
// 529.598 us; speedup vs baseline: 16.0149x; 1.2177x over previous
//
#include <hip/hip_runtime.h>

#define NNODES 50000
#define NEDGES 800000
#define HD 256
#define NSB 196   // scan blocks: 196*256 = 50176 >= NNODES+1
#define BM 112    // gemm rows/block: grid 447 < 512 resident slots -> single round

typedef __attribute__((ext_vector_type(8))) short bf16x8;
typedef __attribute__((ext_vector_type(4))) float f32x4;

__device__ __forceinline__ unsigned int f2bf(float f) {
    union { float f; unsigned int u; } v; v.f = f;
    unsigned int u = v.u;
    u += 0x7fffu + ((u >> 16) & 1u);
    return u >> 16;
}
__device__ __forceinline__ float b2f(unsigned short u) {
    union { unsigned int u; float f; } v; v.u = ((unsigned int)u) << 16;
    return v.f;
}

__global__ void zero_int(int* __restrict__ p, int n) {
    int i = blockIdx.x * blockDim.x + threadIdx.x;
    if (i < n) p[i] = 0;
}

__global__ __launch_bounds__(256) void x2bf(const float* __restrict__ x,
                                            unsigned short* __restrict__ xb) {
    int i = blockIdx.x * 256 + threadIdx.x;
    float4 v = reinterpret_cast<const float4*>(x)[i];
    ushort4 o;
    o.x = (unsigned short)f2bf(v.x);
    o.y = (unsigned short)f2bf(v.y);
    o.z = (unsigned short)f2bf(v.z);
    o.w = (unsigned short)f2bf(v.w);
    reinterpret_cast<ushort4*>(xb)[i] = o;
}

__global__ __launch_bounds__(256) void hist_kernel(const int* __restrict__ dst,
                                                   int* __restrict__ deg) {
    int e = blockIdx.x * 256 + threadIdx.x;
    if (e < NEDGES) atomicAdd(&deg[dst[e]], 1);
}

// --- 3-kernel exclusive scan of deg[0..NNODES) ---
__global__ __launch_bounds__(256) void scan_part(const int* __restrict__ deg,
                                                 int* __restrict__ bsum) {
    __shared__ int red[256];
    int t = threadIdx.x;
    int i = blockIdx.x * 256 + t;
    red[t] = (i < NNODES) ? deg[i] : 0;
    __syncthreads();
    for (int off = 128; off > 0; off >>= 1) {
        if (t < off) red[t] += red[t + off];
        __syncthreads();
    }
    if (t == 0) bsum[blockIdx.x] = red[0];
}

__global__ __launch_bounds__(256) void scan_base(const int* __restrict__ bsum,
                                                 int* __restrict__ bbase) {
    __shared__ int s[256];
    int t = threadIdx.x;
    int v = (t < NSB) ? bsum[t] : 0;
    s[t] = v;
    __syncthreads();
    for (int off = 1; off < 256; off <<= 1) {
        int u = (t >= off) ? s[t - off] : 0;
        __syncthreads();
        s[t] += u;
        __syncthreads();
    }
    if (t < NSB) bbase[t] = s[t] - v;  // exclusive
}

__global__ __launch_bounds__(256) void scan_fin(const int* __restrict__ deg,
                                                const int* __restrict__ bbase,
                                                int* __restrict__ rowptr,
                                                int* __restrict__ cursor) {
    __shared__ int s[256];
    int t = threadIdx.x;
    int i = blockIdx.x * 256 + t;
    int v = (i < NNODES) ? deg[i] : 0;
    s[t] = v;
    __syncthreads();
    for (int off = 1; off < 256; off <<= 1) {
        int u = (t >= off) ? s[t - off] : 0;
        __syncthreads();
        s[t] += u;
        __syncthreads();
    }
    int val = bbase[blockIdx.x] + s[t] - v;  // exclusive prefix
    if (i < NNODES) {
        rowptr[i] = val;
        cursor[i] = val;
    }
    if (i == NNODES) rowptr[i] = val;
}

__global__ __launch_bounds__(256) void fill_csr(const int* __restrict__ src,
                                                const int* __restrict__ dst,
                                                const float* __restrict__ ea,
                                                int* __restrict__ cursor,
                                                int4* __restrict__ epack) {
    int e = blockIdx.x * 256 + threadIdx.x;
    if (e >= NEDGES) return;
    int pos = atomicAdd(&cursor[dst[e]], 1);
    int4 v;
    v.x = src[e];
    v.y = __float_as_int(ea[e * 3 + 0]);
    v.z = __float_as_int(ea[e * 3 + 1]);
    v.w = __float_as_int(ea[e * 3 + 2]);
    epack[pos] = v;
}

// out[n] = x[n] + sum_{e in CSR[n]} relu(x[src_e] + ea_e @ We + be); bf16 I/O.
// 4-edge unrolled: 4 epack + 4 x-row loads in flight per iteration (MLP=4).
__global__ __launch_bounds__(256) void agg_kernel(
    const unsigned short* __restrict__ xb, const int* __restrict__ rowptr,
    const int4* __restrict__ epack, const float* __restrict__ We,
    const float* __restrict__ be, unsigned short* __restrict__ out) {
    const int wave = threadIdx.x >> 6;
    const int lane = threadIdx.x & 63;
    const int n = blockIdx.x * 4 + wave;
    const int c = lane * 4;
    const float4 w0 = *reinterpret_cast<const float4*>(We + c);
    const float4 w1 = *reinterpret_cast<const float4*>(We + HD + c);
    const float4 w2 = *reinterpret_cast<const float4*>(We + 2 * HD + c);
    const float4 bb = *reinterpret_cast<const float4*>(be + c);
    ushort4 xv = *reinterpret_cast<const ushort4*>(xb + (size_t)n * HD + c);
    float4 acc = make_float4(b2f(xv.x), b2f(xv.y), b2f(xv.z), b2f(xv.w));
    const int beg = rowptr[n], end = rowptr[n + 1];

#define EDGE_ACC(E, XS)                                                              \
    {                                                                                \
        float a0 = __int_as_float((E).y);                                            \
        float a1 = __int_as_float((E).z);                                            \
        float a2 = __int_as_float((E).w);                                            \
        acc.x += fmaxf(fmaf(a0, w0.x, fmaf(a1, w1.x, fmaf(a2, w2.x,                  \
                       b2f((XS).x) + bb.x))), 0.f);                                  \
        acc.y += fmaxf(fmaf(a0, w0.y, fmaf(a1, w1.y, fmaf(a2, w2.y,                  \
                       b2f((XS).y) + bb.y))), 0.f);                                  \
        acc.z += fmaxf(fmaf(a0, w0.z, fmaf(a1, w1.z, fmaf(a2, w2.z,                  \
                       b2f((XS).z) + bb.z))), 0.f);                                  \
        acc.w += fmaxf(fmaf(a0, w0.w, fmaf(a1, w1.w, fmaf(a2, w2.w,                  \
                       b2f((XS).w) + bb.w))), 0.f);                                  \
    }

    int i = beg;
    for (; i + 4 <= end; i += 4) {
        int4 e0 = epack[i];
        int4 e1 = epack[i + 1];
        int4 e2 = epack[i + 2];
        int4 e3 = epack[i + 3];
        ushort4 s0 = *reinterpret_cast<const ushort4*>(xb + (size_t)e0.x * HD + c);
        ushort4 s1 = *reinterpret_cast<const ushort4*>(xb + (size_t)e1.x * HD + c);
        ushort4 s2 = *reinterpret_cast<const ushort4*>(xb + (size_t)e2.x * HD + c);
        ushort4 s3 = *reinterpret_cast<const ushort4*>(xb + (size_t)e3.x * HD + c);
        EDGE_ACC(e0, s0);
        EDGE_ACC(e1, s1);
        EDGE_ACC(e2, s2);
        EDGE_ACC(e3, s3);
    }
    for (; i < end; ++i) {
        int4 e0 = epack[i];
        ushort4 s0 = *reinterpret_cast<const ushort4*>(xb + (size_t)e0.x * HD + c);
        EDGE_ACC(e0, s0);
    }
#undef EDGE_ACC

    ushort4 o;
    o.x = (unsigned short)f2bf(acc.x);
    o.y = (unsigned short)f2bf(acc.y);
    o.z = (unsigned short)f2bf(acc.z);
    o.w = (unsigned short)f2bf(acc.w);
    *reinterpret_cast<ushort4*>(out + (size_t)n * HD + c) = o;
}

// Pack 11 HxH fp32 matrices into bf16 MFMA B-fragment order.
__global__ void pack_w(const float* __restrict__ Wm, const float* __restrict__ pW1,
                       const float* __restrict__ pW2, unsigned short* __restrict__ Wpk) {
    int g = blockIdx.x * 256 + threadIdx.x;  // 11 * 65536
    int mat = g >> 16;
    int r = g & 65535;
    int j = r & 7, lane = (r >> 3) & 63, kb = (r >> 9) & 7, ct = r >> 12;
    int k = kb * 32 + ((lane >> 4) << 3) + j;
    int c = ct * 16 + (lane & 15);
    const float* s = (mat < 9) ? (Wm + (size_t)mat * 65536)
                               : ((mat == 9) ? pW1 : pW2);
    Wpk[g] = (unsigned short)f2bf(s[k * 256 + c]);
}

// Load the 4 B-fragments of one kb-step (64B/lane total).
__device__ __forceinline__ void load_b(const unsigned short* __restrict__ Wp,
                                       int wave, int lane, int kb, bf16x8* dst) {
#pragma unroll
    for (int ct = 0; ct < 4; ++ct)
        dst[ct] = *reinterpret_cast<const bf16x8*>(
            Wp + ((size_t)(((wave * 4 + ct) * 8 + kb) * 64 + lane)) * 8);
}

// Fused NPH-linear chain over a resident BM-row tile (BM=112 -> grid 447 fits
// in one resident round: no dispatch tail). Ring-3 B pipeline, per-wave 7x4
// acc tile (112 VGPRs; total ~220, no spill at the 256 cap).
template <int NPH, bool RELU_LAST, bool RES, bool OUTF32>
__global__ __launch_bounds__(256, 2) void gemm_fused(
    const unsigned short* __restrict__ A, const unsigned short* __restrict__ Wpk,
    const float* __restrict__ b0, const float* __restrict__ b1,
    const float* __restrict__ b2, const unsigned short* __restrict__ res,
    void* __restrict__ outv) {
    __shared__ __align__(16) unsigned char lds[BM * 512];
    const int tid = threadIdx.x;
    const int rbase = blockIdx.x * BM;
    const int wave = tid >> 6;
    const int lane = tid & 63;
    const int lr = lane & 15;
    const int lg = lane >> 4;

    // Prime the ring for phase 0 before staging: latency overlaps A loads.
    bf16x8 bb[3][4];
    load_b(Wpk, wave, lane, 0, bb[0]);
    load_b(Wpk, wave, lane, 1, bb[1]);

    for (int it = 0; it < BM / 4; ++it) {
        int q = tid + it * 256;
        int row = q >> 6;
        int k4 = q & 63;
        int grow = rbase + row;
        uint2 v = make_uint2(0u, 0u);
        if (grow < NNODES)
            v = *reinterpret_cast<const uint2*>(A + (size_t)grow * HD + k4 * 4);
        int off = row * 512 + ((k4 * 8) ^ ((row & 7) << 4));
        *reinterpret_cast<uint2*>(lds + off) = v;
    }
    __syncthreads();

#pragma unroll
    for (int ph = 0; ph < NPH; ++ph) {
        const unsigned short* Wp = Wpk + (size_t)ph * 65536;
        const float* bias = (ph == 0) ? b0 : ((ph == 1) ? b1 : b2);

        f32x4 acc[7][4];
#pragma unroll
        for (int rt = 0; rt < 7; ++rt)
#pragma unroll
            for (int ct = 0; ct < 4; ++ct) acc[rt][ct] = (f32x4){0.f, 0.f, 0.f, 0.f};

#pragma unroll
        for (int kb = 0; kb < 8; ++kb) {
            if (kb + 2 < 8) load_b(Wp, wave, lane, kb + 2, bb[(kb + 2) % 3]);
            bf16x8 a[7];
#pragma unroll
            for (int rt = 0; rt < 7; ++rt) {
                int row = rt * 16 + lr;
                int kbyte = kb * 64 + lg * 16;
                int off = row * 512 + (kbyte ^ ((row & 7) << 4));
                a[rt] = *reinterpret_cast<const bf16x8*>(lds + off);
            }
#pragma unroll
            for (int rt = 0; rt < 7; ++rt)
#pragma unroll
                for (int ct = 0; ct < 4; ++ct)
                    acc[rt][ct] = __builtin_amdgcn_mfma_f32_16x16x32_bf16(
                        a[rt], bb[kb % 3][ct], acc[rt][ct], 0, 0, 0);
        }

        if (ph < NPH - 1) {
            __syncthreads();  // all waves done reading this phase's tile
#pragma unroll
            for (int rt = 0; rt < 7; ++rt) {
#pragma unroll
                for (int ct = 0; ct < 4; ++ct) {
                    int c = wave * 64 + ct * 16 + lr;
                    float bv = bias[c];
#pragma unroll
                    for (int i = 0; i < 4; ++i) {
                        int row = rt * 16 + lg * 4 + i;
                        float v = fmaxf(acc[rt][ct][i] + bv, 0.f);
                        int off = row * 512 + ((2 * c) ^ ((row & 7) << 4));
                        *reinterpret_cast<unsigned short*>(lds + off) =
                            (unsigned short)f2bf(v);
                    }
                }
            }
            // Prime the ring for the next phase while waiting at the barrier.
            const unsigned short* Wn = Wpk + (size_t)(ph + 1) * 65536;
            load_b(Wn, wave, lane, 0, bb[0]);
            load_b(Wn, wave, lane, 1, bb[1]);
            __syncthreads();
        } else {
#pragma unroll
            for (int rt = 0; rt < 7; ++rt) {
                int row0 = rbase + rt * 16 + lg * 4;
#pragma unroll
                for (int ct = 0; ct < 4; ++ct) {
                    int c = wave * 64 + ct * 16 + lr;
                    float bv = bias[c];
#pragma unroll
                    for (int i = 0; i < 4; ++i) {
                        int row = row0 + i;
                        if (row < NNODES) {
                            float v = acc[rt][ct][i] + bv;
                            if (RELU_LAST) v = fmaxf(v, 0.f);
                            if (RES) v += b2f(res[(size_t)row * HD + c]);
                            if (OUTF32)
                                reinterpret_cast<float*>(outv)[(size_t)row * HD + c] = v;
                            else
                                reinterpret_cast<unsigned short*>(
                                    outv)[(size_t)row * HD + c] =
                                    (unsigned short)f2bf(v);
                        }
                    }
                }
            }
        }
    }
}

extern "C" void kernel_launch(void* const* d_in, const int* in_sizes, int n_in,
                              void* d_out, int out_size, void* d_ws, size_t ws_size,
                              hipStream_t stream) {
    const float* x   = (const float*)d_in[0];
    const int*   ei  = (const int*)d_in[1];
    const float* ea  = (const float*)d_in[2];
    const float* We  = (const float*)d_in[3];
    const float* be  = (const float*)d_in[4];
    const float* Wm  = (const float*)d_in[5];
    const float* bm  = (const float*)d_in[6];
    const float* pW1 = (const float*)d_in[7];
    const float* pb1 = (const float*)d_in[8];
    const float* pW2 = (const float*)d_in[9];
    const float* pb2 = (const float*)d_in[10];
    float* out = (float*)d_out;

    const size_t NH = (size_t)NNODES * HD;
    unsigned short* xb   = (unsigned short*)d_ws;
    unsigned short* curb = xb + NH;
    unsigned short* aggb = curb + NH;
    unsigned short* Wpk  = aggb + NH;           // 11*65536 shorts
    int* rowptr = (int*)(Wpk + 11 * 65536);     // NNODES+1
    int* cursor = rowptr + 50004;
    int* deg    = cursor + 50004;
    int* bsum   = deg + 50004;                  // NSB
    int* bbase  = bsum + 256;
    int4* epack = (int4*)d_out;  // scratch until the head kernel writes d_out

    const int* srcI = ei;
    const int* dstI = ei + NEDGES;

    // --- One-time prep ---
    x2bf<<<dim3(NH / 4 / 256), dim3(256), 0, stream>>>(x, xb);
    zero_int<<<dim3((NNODES + 255) / 256), dim3(256), 0, stream>>>(deg, NNODES);
    pack_w<<<dim3(11 * 65536 / 256), dim3(256), 0, stream>>>(Wm, pW1, pW2, Wpk);
    hist_kernel<<<dim3((NEDGES + 255) / 256), dim3(256), 0, stream>>>(dstI, deg);
    scan_part<<<dim3(NSB), dim3(256), 0, stream>>>(deg, bsum);
    scan_base<<<dim3(1), dim3(256), 0, stream>>>(bsum, bbase);
    scan_fin<<<dim3(NSB), dim3(256), 0, stream>>>(deg, bbase, rowptr, cursor);
    fill_csr<<<dim3((NEDGES + 255) / 256), dim3(256), 0, stream>>>(srcI, dstI, ea,
                                                                   cursor, epack);

    const int gemm_grid = (NNODES + BM - 1) / BM;  // 447
    for (int l = 0; l < 3; ++l) {
        const unsigned short* xin = (l == 0) ? xb : curb;
        agg_kernel<<<dim3(NNODES / 4), dim3(256), 0, stream>>>(
            xin, rowptr, epack, We + (size_t)l * 3 * HD, be + (size_t)l * HD, aggb);
        gemm_fused<3, true, true, false><<<dim3(gemm_grid), dim3(256), 0, stream>>>(
            aggb, Wpk + (size_t)l * 3 * 65536, bm + (size_t)(l * 3 + 0) * HD,
            bm + (size_t)(l * 3 + 1) * HD, bm + (size_t)(l * 3 + 2) * HD, xin, curb);
    }
    gemm_fused<2, false, false, true><<<dim3(gemm_grid), dim3(256), 0, stream>>>(
        curb, Wpk + (size_t)9 * 65536, pb1, pb2, nullptr, nullptr, out);
}